// Round 14
// baseline (526.824 us; speedup 1.0000x reference)
//
#include <hip/hip_runtime.h>
#include <hip/hip_bf16.h>
#include <math.h>

#define NBATCH 8
#define NBOX   20000
#define NCLS   80
#define NREL   51
#define MAXDET 300
#define NTOT   (NCLS * MAXDET)      // 24000
#define CAP    512
#define SPECCAP 2560
#define NHB    3584                 // 512-ULP buckets over (0.9, 1.0]; 512|NHB, 256|NHB
#define HB0    (0x3F666666u >> 9)   // bucket base = bits(0.9f) >> 9
#define TARGETK 480u
#define SCORE_THR 0.05f
#define SPEC_THRF 0.9f
#define WWAVES 8
#define QPB    5120                 // float4 per k_scatter block
#define QTOT   (NBOX * NCLS / 4)    // 400000 float4 per batch

typedef unsigned long long u64;
typedef unsigned int u32;

// IoU > 0.5, explicit IEEE div (slow path only).
__device__ __forceinline__ bool iou_sup(float ax1, float ay1, float ax2, float ay2, float aarea,
                                        float bx1, float by1, float bx2, float by2, float barea) {
  float ix1 = fmaxf(ax1, bx1);
  float iy1 = fmaxf(ay1, by1);
  float ix2 = fminf(ax2, bx2);
  float iy2 = fminf(ay2, by2);
  float dw = fmaxf(__fsub_rn(ix2, ix1), 0.0f);
  float dh = fmaxf(__fsub_rn(iy2, iy1), 0.0f);
  float inter = __fmul_rn(dw, dh);
  float uni = __fsub_rn(__fadd_rn(aarea, barea), inter);
  if (!(uni > 0.0f)) return false;
  return __fdiv_rn(inter, uni) > 0.5f;
}

__device__ __forceinline__ bool iou_gt_half(float ax1, float ay1, float ax2, float ay2,
                                            float bx1, float by1, float bx2, float by2) {
  float aa = __fmul_rn(__fsub_rn(ax2, ax1), __fsub_rn(ay2, ay1));
  float ab = __fmul_rn(__fsub_rn(bx2, bx1), __fsub_rn(by2, by1));
  return iou_sup(ax1, ay1, ax2, ay2, aa, bx1, by1, bx2, by2, ab);
}

// Bit-exact div-free IoU>0.5 in PURE f32:
//   rn32(inter/uni) > 0.5  ⟺  inter/uni > 0.5(1+2^-24)   (tie->even = 0.5)
//   f32 test inter > 0.5*uni differs only if a float inter lies in
//   (0.5uni, 0.5uni(1+2^-24)] — impossible: succ(a) = a(1+2^-23/m), m<2.
__device__ __forceinline__ bool iou_sup_fast(float ax1, float ay1, float ax2, float ay2,
                                             float aarea, float bx1, float by1, float bx2,
                                             float by2, float barea) {
  float ix1 = fmaxf(ax1, bx1);
  float iy1 = fmaxf(ay1, by1);
  float ix2 = fminf(ax2, bx2);
  float iy2 = fminf(ay2, by2);
  float dw = fmaxf(__fsub_rn(ix2, ix1), 0.0f);
  float dh = fmaxf(__fsub_rn(iy2, iy1), 0.0f);
  float inter = __fmul_rn(dw, dh);
  float uni = __fsub_rn(__fadd_rn(aarea, barea), inter);
  return (uni > 0.0f) && (inter > __fmul_rn(0.5f, uni));
}

#define CEXR(x, y, asc) { bool sw_ = (asc) ? ((x) > (y)) : ((x) < (y)); \
                          if (sw_) { u64 t_ = (x); (x) = (y); (y) = t_; } }

// Bitonic sort ascending over SZ u64 keys in LDS.
template <int THREADS>
__device__ __forceinline__ void bitonic_sort(u64* keys, int SZ, int tid) {
  for (int k = 2; k <= SZ; k <<= 1) {
    for (int j = k >> 1; j >= 4; j >>= 1) {
      for (int v = tid; v < (SZ >> 1); v += THREADS) {
        int i = ((v & ~(j - 1)) << 1) | (v & (j - 1));
        int p = i | j;
        bool asc = ((i & k) == 0);
        u64 a = keys[i], b = keys[p];
        bool sw = asc ? (a > b) : (a < b);
        if (sw) { keys[i] = b; keys[p] = a; }
      }
      __syncthreads();
    }
    if (tid < (SZ >> 2)) {
      ulonglong2* k2 = (ulonglong2*)keys;
      ulonglong2 lo = k2[tid * 2], hi = k2[tid * 2 + 1];
      u64 a = lo.x, b = lo.y, c = hi.x, d = hi.y;
      int i0 = tid << 2;
      if (k == 2) {
        CEXR(a, b, true); CEXR(c, d, false);
      } else {
        bool asc = ((i0 & k) == 0);
        CEXR(a, c, asc); CEXR(b, d, asc);  // j = 2
        CEXR(a, b, asc); CEXR(c, d, asc);  // j = 1
      }
      lo.x = a; lo.y = b; hi.x = c; hi.y = d;
      k2[tid * 2] = lo; k2[tid * 2 + 1] = hi;
    }
    __syncthreads();
  }
}

// Barrier-light suffix select over NB buckets (LDS or global hist):
// minimal suffix >= min(total, cap). sout: [0]=bucket [1]=sel [2]=above [3]=total.
template <int NB, int THREADS>
__device__ __forceinline__ void suffix_fast(const u32* hist, u32 cap, u32* wsum, u32* sout) {
  const int tid = threadIdx.x, lane = tid & 63, w = tid >> 6;
  const int NW = THREADS / 64;
  const int G = NB / THREADS;
  u32 v = 0;
  const int hb = tid * G;
#pragma unroll
  for (int t = 0; t < G; ++t) v += hist[hb + t];
  u32 s = v;
#pragma unroll
  for (int off = 1; off < 64; off <<= 1) {
    u32 t2 = __shfl_down(s, off);
    if (lane + off < 64) s += t2;
  }
  if (lane == 0) wsum[w] = s;
  __syncthreads();
  u32 total = 0;
#pragma unroll
  for (int ww = 0; ww < NW; ++ww) total += wsum[ww];
  u32 after = 0;
#pragma unroll
  for (int ww = 1; ww < NW; ++ww) if (ww > w) after += wsum[ww];
  u32 inc = s + after;
  u32 exc = inc - v;
  if (tid == 0) {
    sout[3] = total;
    if (total == 0u) { sout[0] = 0u; sout[1] = 0u; sout[2] = 0u; }
  }
  u32 target = total < cap ? total : cap;
  if (total != 0u && inc >= target && exc < target) {  // exactly one thread
    u32 acc = exc;
    for (int u = hb + G - 1; u >= hb; --u) {
      acc += hist[u];
      if (acc >= target) { sout[0] = (u32)u; sout[1] = acc; sout[2] = acc - hist[u]; break; }
    }
  }
  __syncthreads();
}

// Zero all per-launch scratch (counters + per-batch top-k histogram).
__global__ __launch_bounds__(256) void k_init(u32* __restrict__ ghist,
                                              u32* __restrict__ gtail,
                                              u32* __restrict__ bucketCnt,
                                              u32* __restrict__ totCnt) {
  const int b = blockIdx.x;
  const int tid = threadIdx.x;
  for (int i = tid; i < NHB; i += 256) ghist[b * NHB + i] = 0u;
  if (tid == 0) gtail[b] = 0u;
  for (int i = tid; i < NCLS; i += 256) {
    bucketCnt[b * NCLS + i] = 0u;
    totCnt[b * NCLS + i] = 0u;
  }
}

// Single coalesced pass over cls in native (N,C) layout: scatter spec (>0.9) keys
// into per-(b,c) global buckets (order arbitrary — later sort canonicalizes) and
// accumulate per-class counts of s > 0.05 (LDS counters -> 80 global atomics).
__global__ __launch_bounds__(256) void k_scatter(const float* __restrict__ cls,
                                                 u64* __restrict__ bucketKeys,
                                                 u32* __restrict__ bucketCnt,
                                                 u32* __restrict__ totCnt) {
  __shared__ u32 cnt80[NCLS];
  const int tid = threadIdx.x;
  const int b = blockIdx.y;
  const int q0 = blockIdx.x * QPB;
  const int qend = (q0 + QPB < QTOT) ? (q0 + QPB) : QTOT;
  const float4* src = (const float4*)(cls + (size_t)b * NBOX * NCLS);
  for (int i = tid; i < NCLS; i += 256) cnt80[i] = 0u;
  __syncthreads();

  for (int base = q0; base < qend; base += 2048) {
    float4 v[8];
#pragma unroll
    for (int p = 0; p < 8; ++p) {
      int q = base + tid + (p << 8);
      if (q < qend) v[p] = src[q];
    }
#pragma unroll
    for (int p = 0; p < 8; ++p) {
      int q = base + tid + (p << 8);
      if (q < qend) {
        // C=80 divisible by 4 -> a float4 never crosses a row boundary.
        int n = q / (NCLS / 4);
        int cb = (q % (NCLS / 4)) * 4;
        float vv[4] = {v[p].x, v[p].y, v[p].z, v[p].w};
#pragma unroll
        for (int e = 0; e < 4; ++e) {
          float s = vv[e];
          if (s > SCORE_THR) {
            atomicAdd(&cnt80[cb + e], 1u);
            if (s > SPEC_THRF) {
              int bkt = b * NCLS + cb + e;
              u32 pos = atomicAdd(&bucketCnt[bkt], 1u);
              if (pos < SPECCAP)
                bucketKeys[(size_t)bkt * SPECCAP + pos] =
                    ((u64)__float_as_uint(s) << 32) | (~(u32)n);
            }
          }
        }
      }
    }
  }
  __syncthreads();
  for (int c = tid; c < NCLS; c += 256) {
    u32 v = cnt80[c];
    if (v) atomicAdd(&totCnt[b * NCLS + c], v);
  }
}

// Exact reference-style greedy NMS (slow path), 512-thread, inline from k_nms.
__device__ void slow_path(const float* __restrict__ boxes,
                          const float* __restrict__ cls, int bc,
                          float* __restrict__ keptScore, int* __restrict__ keptN,
                          int* __restrict__ keptCount,
                          u32* __restrict__ ghist, u32* __restrict__ gtail,
                          char* smem) {
  u32* sup = (u32*)smem;                       // [(NBOX+31)/32] = 625 u32 @0
  u64* red = (u64*)(smem + 2560);              // [512] u64 @2560
  float4* sbx = (float4*)(smem + 6656);        // @6656 (16B aligned)
  int* s_kept = (int*)(smem + 6672);
  const int tid = threadIdx.x;
  const int b = bc / NCLS, c = bc % NCLS;
  const float* col = cls + (size_t)b * NBOX * NCLS + c;

  for (int i = tid; i < (NBOX + 31) / 32; i += 512) sup[i] = 0u;
  if (tid == 0) *s_kept = 0;
  __syncthreads();
  for (int it = 0; it < MAXDET; ++it) {
    u64 best = 0ull;
    for (int n = tid; n < NBOX; n += 512) {
      if ((sup[n >> 5] >> (n & 31)) & 1u) continue;
      float s = col[(size_t)n * NCLS];
      if (s > SCORE_THR) {
        u64 key = ((u64)__float_as_uint(s) << 32) | (~(u32)n);
        if (key > best) best = key;
      }
    }
    red[tid] = best;
    __syncthreads();
    for (int off = 256; off > 0; off >>= 1) {
      if (tid < off) { u64 o = red[tid + off]; if (o > red[tid]) red[tid] = o; }
      __syncthreads();
    }
    u64 win = red[0];
    if (win == 0ull) break;
    u32 nw = ~((u32)win);
    if (tid == 0) {
      int k = *s_kept;
      keptScore[bc * MAXDET + k] = __uint_as_float((u32)(win >> 32));
      keptN[bc * MAXDET + k] = (int)nw;
      *s_kept = k + 1;
      *sbx = ((const float4*)boxes)[(size_t)b * NBOX + nw];
    }
    __syncthreads();
    float4 bx = *sbx;
    for (int n = tid; n < NBOX; n += 512) {
      float4 cb = ((const float4*)boxes)[(size_t)b * NBOX + n];
      if (iou_gt_half(bx.x, bx.y, bx.z, bx.w, cb.x, cb.y, cb.z, cb.w))
        atomicOr(&sup[n >> 5], 1u << (n & 31));
    }
    if (tid == 0) atomicOr(&sup[nw >> 5], 1u << (nw & 31));
    __syncthreads();
  }
  __syncthreads();
  const int kept = *s_kept;
  for (int r = kept + tid; r < MAXDET; r += 512) {
    keptScore[bc * MAXDET + r] = -INFINITY;
    keptN[bc * MAXDET + r] = 0;
  }
  for (int rr = tid; rr < kept; rr += 512) {
    float s = keptScore[bc * MAXDET + rr];
    if (s > SPEC_THRF) {
      u32 h = (__float_as_uint(s) >> 9) - HB0;
      if (h > NHB - 1) h = NHB - 1;
      atomicAdd(&ghist[b * NHB + h], 1u);
    } else {
      atomicAdd(&gtail[b], 1u);
    }
  }
  if (tid == 0) keptCount[bc] = kept;
}

// Fused per-(b,c) kernel: bucket load -> LDS histogram top-~480 select -> compact ->
// bitonic-512 -> round-13 tile-parallel greedy walk. Slow path inline on any
// speculation failure. On success, histograms kept scores for the batch top-k.
__global__ __launch_bounds__(512) void k_nms(const float* __restrict__ boxes,
                                             const float* __restrict__ cls,
                                             const u64* __restrict__ bucketKeys,
                                             const u32* __restrict__ bucketCnt,
                                             const u32* __restrict__ totCnt,
                                             float* __restrict__ keptScore,
                                             int* __restrict__ keptN,
                                             int* __restrict__ keptCount,
                                             u32* __restrict__ ghist,
                                             u32* __restrict__ gtail) {
  // Select layout: side u64[2560]@0 (20480); hist u32[3584]@20480 (14336) -> 34816;
  //                keys u64[512]@34816 (4096) -> 38912.
  // Walk aliasing (side/hist dead): candbox f4[512]@0; carea@8192; keptbox@10240;
  //                karea@15040; kn@16240; ksc@17440 (ends 18640 < 20480). keys stays.
  // Slow aliasing: sup@0; red@2560; sbx@6656; s_kept@6672.
  __shared__ __align__(16) char smem[38912];
  u64* side = (u64*)smem;
  u32* hist = (u32*)(smem + 20480);
  u64* keys = (u64*)(smem + 34816);
  float4* candbox = (float4*)smem;
  float* carea = (float*)(smem + 8192);
  float4* keptbox = (float4*)(smem + 10240);
  float* karea = (float*)(smem + 15040);
  int* kn = (int*)(smem + 16240);
  float* ksc = (float*)(smem + 17440);
  __shared__ u32 wsum[WWAVES], selB[4];
  __shared__ u32 s_cnt;
  __shared__ u64 supW[WWAVES];
  __shared__ u64 mpart[WWAVES][64];
  __shared__ int s_kept;

  const int tid = threadIdx.x;
  const int lane = tid & 63;
  const int w = tid >> 6;
  const u64 lmask = (1ull << lane) - 1ull;
  const int bc = blockIdx.x;
  const int b = bc / NCLS;

  const u32 specRaw = bucketCnt[bc];
  const u32 totalAll = totCnt[bc];

  if (totalAll == 0u) {
    for (int r = tid; r < MAXDET; r += 512) {
      keptScore[bc * MAXDET + r] = -INFINITY;
      keptN[bc * MAXDET + r] = 0;
    }
    if (tid == 0) keptCount[bc] = 0;
    return;
  }
  const u32 target = totalAll < TARGETK ? totalAll : TARGETK;
  if (specRaw > SPECCAP || specRaw < target) {  // speculation failed: exact path
    slow_path(boxes, cls, bc, keptScore, keptN, keptCount, ghist, gtail, smem);
    return;
  }
  const u32 specCount = specRaw;

  // Load bucket + build 512-ULP histogram.
  const u64* bk = bucketKeys + (size_t)bc * SPECCAP;
  for (int i = tid; i < (int)specCount; i += 512) side[i] = bk[i];
  for (int i = tid; i < NHB; i += 512) hist[i] = 0u;
  if (tid == 0) { s_cnt = 0u; s_kept = 0; }
  __syncthreads();
  for (int i = tid; i < (int)specCount; i += 512) {
    u32 bits = (u32)(side[i] >> 32);
    u32 h = (bits >> 9) - HB0;
    if (h > NHB - 1) h = NHB - 1;
    atomicAdd(&hist[h], 1u);
  }
  __syncthreads();

  suffix_fast<NHB, 512>(hist, target, wsum, selB);
  const u32 F0 = selB[0];
  const u32 selCount = selB[1];
  if (selCount > CAP) {  // tie pile-up beyond sort capacity
    __syncthreads();
    slow_path(boxes, cls, bc, keptScore, keptN, keptCount, ghist, gtail, smem);
    return;
  }

  // Compact selected (h >= F0) into keys, wave-aggregated.
  const int iters = (int)((specCount + 511u) >> 9);
  for (int it2 = 0; it2 < iters; ++it2) {
    u32 idx = (u32)it2 * 512u + (u32)tid;
    bool act = idx < specCount;
    u64 key = act ? side[idx] : 0ull;
    u32 bits = (u32)(key >> 32);
    u32 h = (bits >> 9) - HB0;
    if (h > NHB - 1) h = NHB - 1;
    bool sel = act && (h >= F0);
    u64 ms = __ballot(sel);
    if (ms) {
      u32 bs;
      if (lane == 0) bs = atomicAdd(&s_cnt, (u32)__popcll(ms));
      bs = __shfl(bs, 0);
      if (sel) keys[bs + (u32)__popcll(ms & lmask)] = key;
    }
  }
  __syncthreads();
  for (int i = (int)selCount + tid; i < CAP; i += 512) keys[i] = 0ull;
  __syncthreads();

  bitonic_sort<512>(keys, CAP, tid);

  // Gather candidate boxes (side region dead; candbox/carea alias it).
  for (int i = tid; i < (int)selCount; i += 512) {
    int pos = CAP - 1 - i;
    u32 n = ~((u32)keys[pos]);
    float4 bb = ((const float4*)boxes)[(size_t)b * NBOX + n];
    candbox[pos] = bb;
    carea[pos] = __fmul_rn(__fsub_rn(bb.z, bb.x), __fsub_rn(bb.w, bb.y));
  }
  __syncthreads();

  // Tile-parallel greedy walk (round-13 structure, frozen).
  const u32 ntile = (selCount + 63u) >> 6;
  for (u32 t = 0; t < ntile; ++t) {
    const int kept0 = s_kept;
    if (kept0 >= MAXDET) break;
    const u32 r = t * 64u + (u32)lane;
    const bool valid = r < selCount;
    const int si = valid ? (CAP - 1 - (int)r) : (CAP - 1);
    float4 mybox = candbox[si];
    float marea = carea[si];
    bool sup = false;
    for (int k = w; k < kept0; k += WWAVES) {
      float4 kb = keptbox[k];
      if (iou_sup_fast(kb.x, kb.y, kb.z, kb.w, karea[k],
                       mybox.x, mybox.y, mybox.z, mybox.w, marea))
        sup = true;
    }
    u64 bal = __ballot(sup);
    if (lane == 0) supW[w] = bal;
    u64 mw = 0ull;
    const int ebase = w * 8;
#pragma unroll
    for (int ee = 0; ee < 8; ++ee) {
      const int e = ebase + ee;
      int ei = CAP - 1 - (int)(t * 64u) - e;
      float4 eb = candbox[ei];
      if (e < lane && iou_sup_fast(eb.x, eb.y, eb.z, eb.w, carea[ei],
                                   mybox.x, mybox.y, mybox.z, mybox.w, marea))
        mw |= 1ull << e;
    }
    mpart[w][lane] = mw;
    __syncthreads();
    if (w == 0) {
      u64 prior = 0ull, m = 0ull;
#pragma unroll
      for (int ww = 0; ww < WWAVES; ++ww) {
        prior |= supW[ww];
        m |= mpart[ww][lane];
      }
      u64 remaining = __ballot(valid) & ~prior;
      u64 keptmask = 0ull;
      const int room = MAXDET - kept0;
      while (remaining != 0ull && (int)__popcll(keptmask) < room) {
        int j = __ffsll((long long)remaining) - 1;
        keptmask |= 1ull << j;
        remaining &= ~(1ull << j);
        u64 supj = __ballot(((m >> j) & 1ull) != 0ull);
        remaining &= ~supj;
      }
      if ((keptmask >> lane) & 1ull) {
        int pos = kept0 + (int)__popcll(keptmask & lmask);
        u64 mykey = keys[CAP - 1 - (int)r];
        keptbox[pos] = mybox;
        karea[pos] = marea;
        kn[pos] = (int)(~((u32)mykey));
        ksc[pos] = __uint_as_float((u32)(mykey >> 32));
      }
      if (lane == 0) s_kept = kept0 + (int)__popcll(keptmask);
    }
    __syncthreads();
  }

  const int kept = s_kept;
  const bool exhausted = (kept < MAXDET && selCount < totalAll);
  if (exhausted) {  // prefix exhausted: redo exactly, inline
    __syncthreads();
    slow_path(boxes, cls, bc, keptScore, keptN, keptCount, ghist, gtail, smem);
    return;
  }
  for (int rr = tid; rr < MAXDET; rr += 512) {
    keptScore[bc * MAXDET + rr] = (rr < kept) ? ksc[rr] : -INFINITY;
    keptN[bc * MAXDET + rr] = (rr < kept) ? kn[rr] : 0;
  }
  if (tid == 0) keptCount[bc] = kept;
  for (int rr = tid; rr < kept; rr += 512) {  // top-k histogram contribution
    float s = ksc[rr];
    if (s > SPEC_THRF) {
      u32 h = (__float_as_uint(s) >> 9) - HB0;
      if (h > NHB - 1) h = NHB - 1;
      atomicAdd(&ghist[b * NHB + h], 1u);
    } else {
      atomicAdd(&gtail[b], 1u);
    }
  }
}

// Top-k + outputs: suffix-select from prebuilt per-batch hist -> compact scan ->
// bitonic-512 (exact lax.top_k ties) -> emit. Fallback: exact serial 80-way merge.
__global__ __launch_bounds__(256) void k_osort(const float* __restrict__ boxes,
                                               const float* __restrict__ rel,
                                               const float* __restrict__ keptScore,
                                               const int* __restrict__ keptN,
                                               const u32* __restrict__ ghist,
                                               const u32* __restrict__ gtail,
                                               float* __restrict__ out) {
  __shared__ u64 keys[1024];
  __shared__ u32 wsum[4], selB[4];
  __shared__ u32 s_cnt;
  const int tid = threadIdx.x;
  const int lane = tid & 63;
  const u64 lmask = (1ull << lane) - 1ull;
  const int b = blockIdx.x;
  const float4* ks4 = (const float4*)(keptScore + (size_t)b * NTOT);

  if (tid == 0) s_cnt = 0u;
  suffix_fast<NHB, 256>(ghist + (size_t)b * NHB, (u32)MAXDET, wsum, selB);
  const u32 specTotal = selB[3];
  const u32 totalAll = specTotal + gtail[b];
  const u32 target = totalAll < (u32)MAXDET ? totalAll : (u32)MAXDET;
  const u32 F0 = selB[0];
  const u32 selSpec = selB[1];
  const bool fast = (totalAll != 0u) && (specTotal >= target) && (selSpec <= (u32)CAP);
  int SZ = CAP;

  if (totalAll != 0u) {
    if (fast) {
      for (int base = 0; base < NTOT / 4; base += 2048) {
        float4 v[8];
#pragma unroll
        for (int p = 0; p < 8; ++p) {
          int q = base + tid + (p << 8);
          if (q < NTOT / 4) v[p] = ks4[q];
        }
#pragma unroll
        for (int p = 0; p < 8; ++p) {
          int q = base + tid + (p << 8);
          if (q < NTOT / 4) {
            float vv[4] = {v[p].x, v[p].y, v[p].z, v[p].w};
#pragma unroll
            for (int e = 0; e < 4; ++e) {
              float s = vv[e];
              bool sel = false;
              u32 bits = 0;
              if (s > SPEC_THRF) {
                bits = __float_as_uint(s);
                u32 h = (bits >> 9) - HB0;
                if (h > NHB - 1) h = NHB - 1;
                sel = (h >= F0);
              }
              u64 ms = __ballot(sel);
              if (ms) {
                u32 bs;
                if (lane == 0) bs = atomicAdd(&s_cnt, (u32)__popcll(ms));
                bs = __shfl(bs, 0);
                if (sel)
                  keys[bs + (u32)__popcll(ms & lmask)] =
                      ((u64)bits << 32) | (~(u32)(q * 4 + e));
              }
            }
          }
        }
      }
      __syncthreads();
      for (int i = (int)selSpec + tid; i < CAP; i += 256) keys[i] = 0ull;
      __syncthreads();
      bitonic_sort<256>(keys, CAP, tid);
      SZ = CAP;
    } else {
      // Exact fallback: serial 80-way merge of the sorted per-class lists.
      if (tid < 64) {
        const int c0 = lane, c1 = 64 + lane;
        const bool has1 = (c1 < NCLS);
        const float* ls0 = keptScore + ((size_t)b * NCLS + c0) * MAXDET;
        const float* ls1 = keptScore + ((size_t)b * NCLS + (has1 ? c1 : c0)) * MAXDET;
        int h0 = 0, h1 = 0;
        float v0 = ls0[0], w0v = ls0[1];
        float v1 = has1 ? ls1[0] : -INFINITY;
        float w1v = has1 ? ls1[1] : -INFINITY;
        for (int r = 0; r < (int)target; ++r) {
          float bs; int bcl;
          if (has1 && v1 > v0) { bs = v1; bcl = c1; } else { bs = v0; bcl = c0; }
#pragma unroll
          for (int off = 32; off > 0; off >>= 1) {
            float os = __shfl_xor(bs, off);
            int oc = __shfl_xor(bcl, off);
            if (os > bs || (os == bs && oc < bcl)) { bs = os; bcl = oc; }
          }
          if (bcl == c0) {
            keys[1023 - r] = ((u64)__float_as_uint(bs) << 32) | (~(u32)(c0 * MAXDET + h0));
            ++h0; v0 = w0v; w0v = (h0 + 1 < MAXDET) ? ls0[h0 + 1] : -INFINITY;
          } else if (has1 && bcl == c1) {
            keys[1023 - r] = ((u64)__float_as_uint(bs) << 32) | (~(u32)(c1 * MAXDET + h1));
            ++h1; v1 = w1v; w1v = (h1 + 1 < MAXDET) ? ls1[h1 + 1] : -INFINITY;
          }
        }
      }
      __syncthreads();
      SZ = 1024;
    }
  }

  for (int r = tid; r < MAXDET; r += 256) {
    const bool valid = (u32)r < target;
    float s = -1.0f, pm = -1.0f, pl = -1.0f, cl = -1.0f;
    float4 ob; ob.x = ob.y = ob.z = ob.w = -1.0f;
    if (valid) {
      u64 key = keys[SZ - 1 - r];
      u32 fp = ~((u32)key);
      int c = (int)(fp / MAXDET);
      int slot = (int)(fp - (u32)c * MAXDET);
      int n = keptN[((size_t)b * NCLS + c) * MAXDET + slot];
      s = __uint_as_float((u32)(key >> 32));
      cl = (float)c;
      size_t nb = (size_t)b * NBOX + (u32)n;
      ob = ((const float4*)boxes)[nb];
      const float* rp = rel + nb * NREL;
      float vr[NREL];
#pragma unroll
      for (int p = 0; p < NREL; ++p) vr[p] = rp[p];  // all loads in flight
      float best = vr[0]; int bi = 0;
#pragma unroll
      for (int p = 1; p < NREL; ++p) { if (vr[p] > best) { best = vr[p]; bi = p; } }
      pm = best; pl = (float)bi;
    }
    ((float4*)out)[(size_t)b * MAXDET + r] = ob;
    const int sbase = NBATCH * MAXDET * 4;
    out[sbase + b * MAXDET + r] = s;
    out[sbase + NBATCH * MAXDET + b * MAXDET + r] = cl;
    out[sbase + 2 * NBATCH * MAXDET + b * MAXDET + r] = pm;
    out[sbase + 3 * NBATCH * MAXDET + b * MAXDET + r] = pl;
  }
}

extern "C" void kernel_launch(void* const* d_in, const int* in_sizes, int n_in,
                              void* d_out, int out_size, void* d_ws, size_t ws_size,
                              hipStream_t stream) {
  (void)in_sizes; (void)n_in; (void)out_size; (void)ws_size;
  const float* boxes = (const float*)d_in[0];
  const float* cls   = (const float*)d_in[1];
  const float* rel   = (const float*)d_in[2];
  float* out = (float*)d_out;
  char* ws = (char*)d_ws;

  const size_t NP = NBATCH * NCLS;  // 640 problems
  size_t off = 0;
  const size_t oKeptScore = off; off += NP * MAXDET * 4;          // 768000
  const size_t oKeptN     = off; off += NP * MAXDET * 4;          // 768000
  const size_t oKeptCount = off; off += NP * 4;
  const size_t oBucketCnt = off; off += NP * 4;
  const size_t oTotCnt    = off; off += NP * 4;
  const size_t oGtail     = off; off += NBATCH * 4;
  off = (off + 7) & ~(size_t)7;
  const size_t oGhist     = off; off += (size_t)NBATCH * NHB * 4;
  off = (off + 7) & ~(size_t)7;
  const size_t oBucketKeys = off; off += NP * SPECCAP * 8;        // 13.1 MB

  float* keptScore = (float*)(ws + oKeptScore);
  int* keptN = (int*)(ws + oKeptN);
  int* keptCount = (int*)(ws + oKeptCount);
  u32* bucketCnt = (u32*)(ws + oBucketCnt);
  u32* totCnt = (u32*)(ws + oTotCnt);
  u32* gtail = (u32*)(ws + oGtail);
  u32* ghist = (u32*)(ws + oGhist);
  u64* bucketKeys = (u64*)(ws + oBucketKeys);

  const int qBlocks = (QTOT + QPB - 1) / QPB;  // 79 per batch

  k_init<<<NBATCH, 256, 0, stream>>>(ghist, gtail, bucketCnt, totCnt);
  k_scatter<<<dim3(qBlocks, NBATCH), 256, 0, stream>>>(cls, bucketKeys, bucketCnt, totCnt);
  k_nms<<<NP, 512, 0, stream>>>(boxes, cls, bucketKeys, bucketCnt, totCnt,
                                keptScore, keptN, keptCount, ghist, gtail);
  k_osort<<<NBATCH, 256, 0, stream>>>(boxes, rel, keptScore, keptN, ghist, gtail, out);
}

// Round 15
// 424.988 us; speedup vs baseline: 1.2396x; 1.2396x over previous
//
#include <hip/hip_runtime.h>
#include <hip/hip_bf16.h>
#include <math.h>

#define NBATCH 8
#define NBOX   20000
#define NCLS   80
#define NREL   51
#define MAXDET 300
#define NTOT   (NCLS * MAXDET)      // 24000
#define CAP    512
#define SPECCAP 2560
#define NHB    3584                 // 512-ULP buckets over (0.9, 1.0]; 512|NHB, 256|NHB
#define HB0    (0x3F666666u >> 9)   // bucket base = bits(0.9f) >> 9
#define TARGETK 480u
#define SCORE_THR 0.05f
#define SPEC_THRF 0.9f
#define WWAVES 8

typedef unsigned long long u64;
typedef unsigned int u32;

// IoU > 0.5, explicit IEEE div (slow path only).
__device__ __forceinline__ bool iou_sup(float ax1, float ay1, float ax2, float ay2, float aarea,
                                        float bx1, float by1, float bx2, float by2, float barea) {
  float ix1 = fmaxf(ax1, bx1);
  float iy1 = fmaxf(ay1, by1);
  float ix2 = fminf(ax2, bx2);
  float iy2 = fminf(ay2, by2);
  float dw = fmaxf(__fsub_rn(ix2, ix1), 0.0f);
  float dh = fmaxf(__fsub_rn(iy2, iy1), 0.0f);
  float inter = __fmul_rn(dw, dh);
  float uni = __fsub_rn(__fadd_rn(aarea, barea), inter);
  if (!(uni > 0.0f)) return false;
  return __fdiv_rn(inter, uni) > 0.5f;
}

__device__ __forceinline__ bool iou_gt_half(float ax1, float ay1, float ax2, float ay2,
                                            float bx1, float by1, float bx2, float by2) {
  float aa = __fmul_rn(__fsub_rn(ax2, ax1), __fsub_rn(ay2, ay1));
  float ab = __fmul_rn(__fsub_rn(bx2, bx1), __fsub_rn(by2, by1));
  return iou_sup(ax1, ay1, ax2, ay2, aa, bx1, by1, bx2, by2, ab);
}

// Bit-exact div-free IoU>0.5 in PURE f32:
//   rn32(inter/uni) > 0.5  ⟺  inter/uni > 0.5(1+2^-24)   (tie->even = 0.5)
//   f32 test inter > 0.5*uni differs only if a float inter lies in
//   (0.5uni, 0.5uni(1+2^-24)] — impossible: succ(a) = a(1+2^-23/m), m<2.
__device__ __forceinline__ bool iou_sup_fast(float ax1, float ay1, float ax2, float ay2,
                                             float aarea, float bx1, float by1, float bx2,
                                             float by2, float barea) {
  float ix1 = fmaxf(ax1, bx1);
  float iy1 = fmaxf(ay1, by1);
  float ix2 = fminf(ax2, bx2);
  float iy2 = fminf(ay2, by2);
  float dw = fmaxf(__fsub_rn(ix2, ix1), 0.0f);
  float dh = fmaxf(__fsub_rn(iy2, iy1), 0.0f);
  float inter = __fmul_rn(dw, dh);
  float uni = __fsub_rn(__fadd_rn(aarea, barea), inter);
  return (uni > 0.0f) && (inter > __fmul_rn(0.5f, uni));
}

#define CEXR(x, y, asc) { bool sw_ = (asc) ? ((x) > (y)) : ((x) < (y)); \
                          if (sw_) { u64 t_ = (x); (x) = (y); (y) = t_; } }

// Bitonic sort ascending over SZ u64 keys in LDS.
template <int THREADS>
__device__ __forceinline__ void bitonic_sort(u64* keys, int SZ, int tid) {
  for (int k = 2; k <= SZ; k <<= 1) {
    for (int j = k >> 1; j >= 4; j >>= 1) {
      for (int v = tid; v < (SZ >> 1); v += THREADS) {
        int i = ((v & ~(j - 1)) << 1) | (v & (j - 1));
        int p = i | j;
        bool asc = ((i & k) == 0);
        u64 a = keys[i], b = keys[p];
        bool sw = asc ? (a > b) : (a < b);
        if (sw) { keys[i] = b; keys[p] = a; }
      }
      __syncthreads();
    }
    if (tid < (SZ >> 2)) {
      ulonglong2* k2 = (ulonglong2*)keys;
      ulonglong2 lo = k2[tid * 2], hi = k2[tid * 2 + 1];
      u64 a = lo.x, b = lo.y, c = hi.x, d = hi.y;
      int i0 = tid << 2;
      if (k == 2) {
        CEXR(a, b, true); CEXR(c, d, false);
      } else {
        bool asc = ((i0 & k) == 0);
        CEXR(a, c, asc); CEXR(b, d, asc);  // j = 2
        CEXR(a, b, asc); CEXR(c, d, asc);  // j = 1
      }
      lo.x = a; lo.y = b; hi.x = c; hi.y = d;
      k2[tid * 2] = lo; k2[tid * 2 + 1] = hi;
    }
    __syncthreads();
  }
}

// Barrier-light suffix select over NB buckets (LDS or global hist):
// minimal suffix >= min(total, cap). sout: [0]=bucket [1]=sel [2]=above [3]=total.
template <int NB, int THREADS>
__device__ __forceinline__ void suffix_fast(const u32* hist, u32 cap, u32* wsum, u32* sout) {
  const int tid = threadIdx.x, lane = tid & 63, w = tid >> 6;
  const int NW = THREADS / 64;
  const int G = NB / THREADS;
  u32 v = 0;
  const int hb = tid * G;
#pragma unroll
  for (int t = 0; t < G; ++t) v += hist[hb + t];
  u32 s = v;
#pragma unroll
  for (int off = 1; off < 64; off <<= 1) {
    u32 t2 = __shfl_down(s, off);
    if (lane + off < 64) s += t2;
  }
  if (lane == 0) wsum[w] = s;
  __syncthreads();
  u32 total = 0;
#pragma unroll
  for (int ww = 0; ww < NW; ++ww) total += wsum[ww];
  u32 after = 0;
#pragma unroll
  for (int ww = 1; ww < NW; ++ww) if (ww > w) after += wsum[ww];
  u32 inc = s + after;
  u32 exc = inc - v;
  if (tid == 0) {
    sout[3] = total;
    if (total == 0u) { sout[0] = 0u; sout[1] = 0u; sout[2] = 0u; }
  }
  u32 target = total < cap ? total : cap;
  if (total != 0u && inc >= target && exc < target) {  // exactly one thread
    u32 acc = exc;
    for (int u = hb + G - 1; u >= hb; --u) {
      acc += hist[u];
      if (acc >= target) { sout[0] = (u32)u; sout[1] = acc; sout[2] = acc - hist[u]; break; }
    }
  }
  __syncthreads();
}

// Zero all per-launch scratch (counters + per-batch top-k histogram).
__global__ __launch_bounds__(256) void k_init(u32* __restrict__ ghist,
                                              u32* __restrict__ gtail,
                                              u32* __restrict__ bucketCnt,
                                              u32* __restrict__ totCnt) {
  const int b = blockIdx.x;
  const int tid = threadIdx.x;
  for (int i = tid; i < NHB; i += 256) ghist[b * NHB + i] = 0u;
  if (tid == 0) gtail[b] = 0u;
  for (int i = tid; i < NCLS; i += 256) {
    bucketCnt[b * NCLS + i] = 0u;
    totCnt[b * NCLS + i] = 0u;
  }
}

// Coalesced read of 64x80 cls tile -> padded LDS transpose -> per-class WAVE-
// AGGREGATED push of spec (>0.9) keys (ONE global atomic per class per block,
// compact rank-ordered writes) + per-class >0.05 counts (80 atomics per block).
// Bucket fill order is nondeterministic; downstream count-based selection + full
// sort canonicalize, so results are bit-exact.
__global__ __launch_bounds__(256) void k_gather(const float* __restrict__ cls,
                                                u64* __restrict__ bucketKeys,
                                                u32* __restrict__ bucketCnt,
                                                u32* __restrict__ totCnt) {
  __shared__ float tile[NCLS * 65];
  __shared__ u32 cnt80[NCLS];
  const int tid = threadIdx.x;
  const int lane = tid & 63;
  const int w = tid >> 6;
  const u64 lmask = (1ull << lane) - 1ull;
  const int b = blockIdx.y;
  const int n0 = blockIdx.x * 64;
  const int rows = (NBOX - n0) < 64 ? (NBOX - n0) : 64;
  const float4* src4 = (const float4*)(cls + ((size_t)b * NBOX + n0) * NCLS);
  const int nq = rows * (NCLS / 4);
  for (int i = tid; i < nq; i += 256) {
    int rr = i / (NCLS / 4);
    int c4 = i - rr * (NCLS / 4);
    float4 v = src4[i];
    tile[(c4 * 4 + 0) * 65 + rr] = v.x;
    tile[(c4 * 4 + 1) * 65 + rr] = v.y;
    tile[(c4 * 4 + 2) * 65 + rr] = v.z;
    tile[(c4 * 4 + 3) * 65 + rr] = v.w;
  }
  __syncthreads();

  // Each class row handled by exactly one wave (c = w, w+4, ...).
  for (int c = w; c < NCLS; c += 4) {
    float s = (lane < rows) ? tile[c * 65 + lane] : 0.0f;
    u64 am = __ballot(s > SCORE_THR);
    u64 sm = __ballot(s > SPEC_THRF);
    if (lane == 0) cnt80[c] = (u32)__popcll(am);   // single writer per class
    if (sm) {
      u32 base;
      if (lane == 0)
        base = atomicAdd(&bucketCnt[b * NCLS + c], (u32)__popcll(sm));
      base = __shfl(base, 0);
      if (s > SPEC_THRF) {
        u32 pos = base + (u32)__popcll(sm & lmask);
        if (pos < SPECCAP)
          bucketKeys[(size_t)(b * NCLS + c) * SPECCAP + pos] =
              ((u64)__float_as_uint(s) << 32) | (~(u32)(n0 + lane));
      }
    }
  }
  __syncthreads();
  for (int c = tid; c < NCLS; c += 256) {
    u32 v = cnt80[c];
    if (v) atomicAdd(&totCnt[b * NCLS + c], v);
  }
}

// Exact reference-style greedy NMS (slow path), 512-thread, inline from k_nms.
__device__ void slow_path(const float* __restrict__ boxes,
                          const float* __restrict__ cls, int bc,
                          float* __restrict__ keptScore, int* __restrict__ keptN,
                          int* __restrict__ keptCount,
                          u32* __restrict__ ghist, u32* __restrict__ gtail,
                          char* smem) {
  u32* sup = (u32*)smem;                       // [(NBOX+31)/32] = 625 u32 @0
  u64* red = (u64*)(smem + 2560);              // [512] u64 @2560
  float4* sbx = (float4*)(smem + 6656);        // @6656 (16B aligned)
  int* s_kept = (int*)(smem + 6672);
  const int tid = threadIdx.x;
  const int b = bc / NCLS, c = bc % NCLS;
  const float* col = cls + (size_t)b * NBOX * NCLS + c;

  for (int i = tid; i < (NBOX + 31) / 32; i += 512) sup[i] = 0u;
  if (tid == 0) *s_kept = 0;
  __syncthreads();
  for (int it = 0; it < MAXDET; ++it) {
    u64 best = 0ull;
    for (int n = tid; n < NBOX; n += 512) {
      if ((sup[n >> 5] >> (n & 31)) & 1u) continue;
      float s = col[(size_t)n * NCLS];
      if (s > SCORE_THR) {
        u64 key = ((u64)__float_as_uint(s) << 32) | (~(u32)n);
        if (key > best) best = key;
      }
    }
    red[tid] = best;
    __syncthreads();
    for (int off = 256; off > 0; off >>= 1) {
      if (tid < off) { u64 o = red[tid + off]; if (o > red[tid]) red[tid] = o; }
      __syncthreads();
    }
    u64 win = red[0];
    if (win == 0ull) break;
    u32 nw = ~((u32)win);
    if (tid == 0) {
      int k = *s_kept;
      keptScore[bc * MAXDET + k] = __uint_as_float((u32)(win >> 32));
      keptN[bc * MAXDET + k] = (int)nw;
      *s_kept = k + 1;
      *sbx = ((const float4*)boxes)[(size_t)b * NBOX + nw];
    }
    __syncthreads();
    float4 bx = *sbx;
    for (int n = tid; n < NBOX; n += 512) {
      float4 cb = ((const float4*)boxes)[(size_t)b * NBOX + n];
      if (iou_gt_half(bx.x, bx.y, bx.z, bx.w, cb.x, cb.y, cb.z, cb.w))
        atomicOr(&sup[n >> 5], 1u << (n & 31));
    }
    if (tid == 0) atomicOr(&sup[nw >> 5], 1u << (nw & 31));
    __syncthreads();
  }
  __syncthreads();
  const int kept = *s_kept;
  for (int r = kept + tid; r < MAXDET; r += 512) {
    keptScore[bc * MAXDET + r] = -INFINITY;
    keptN[bc * MAXDET + r] = 0;
  }
  for (int rr = tid; rr < kept; rr += 512) {
    float s = keptScore[bc * MAXDET + rr];
    if (s > SPEC_THRF) {
      u32 h = (__float_as_uint(s) >> 9) - HB0;
      if (h > NHB - 1) h = NHB - 1;
      atomicAdd(&ghist[b * NHB + h], 1u);
    } else {
      atomicAdd(&gtail[b], 1u);
    }
  }
  if (tid == 0) keptCount[bc] = kept;
}

// Fused per-(b,c) kernel: bucket load -> LDS histogram top-~480 select -> compact ->
// bitonic-512 -> round-13 tile-parallel greedy walk. Slow path inline on any
// speculation failure. On success, histograms kept scores for the batch top-k.
__global__ __launch_bounds__(512) void k_nms(const float* __restrict__ boxes,
                                             const float* __restrict__ cls,
                                             const u64* __restrict__ bucketKeys,
                                             const u32* __restrict__ bucketCnt,
                                             const u32* __restrict__ totCnt,
                                             float* __restrict__ keptScore,
                                             int* __restrict__ keptN,
                                             int* __restrict__ keptCount,
                                             u32* __restrict__ ghist,
                                             u32* __restrict__ gtail) {
  // Select layout: side u64[2560]@0 (20480); hist u32[3584]@20480 -> 34816;
  //                keys u64[512]@34816 -> 38912.
  // Walk aliasing (side/hist dead): candbox f4[512]@0; carea@8192; keptbox@10240;
  //                karea@15040; kn@16240; ksc@17440 (ends 18640). keys stays.
  // Slow aliasing: sup@0; red@2560; sbx@6656; s_kept@6672.
  __shared__ __align__(16) char smem[38912];
  u64* side = (u64*)smem;
  u32* hist = (u32*)(smem + 20480);
  u64* keys = (u64*)(smem + 34816);
  float4* candbox = (float4*)smem;
  float* carea = (float*)(smem + 8192);
  float4* keptbox = (float4*)(smem + 10240);
  float* karea = (float*)(smem + 15040);
  int* kn = (int*)(smem + 16240);
  float* ksc = (float*)(smem + 17440);
  __shared__ u32 wsum[WWAVES], selB[4];
  __shared__ u32 s_cnt;
  __shared__ u64 supW[WWAVES];
  __shared__ u64 mpart[WWAVES][64];
  __shared__ int s_kept;

  const int tid = threadIdx.x;
  const int lane = tid & 63;
  const int w = tid >> 6;
  const u64 lmask = (1ull << lane) - 1ull;
  const int bc = blockIdx.x;
  const int b = bc / NCLS;

  const u32 specRaw = bucketCnt[bc];
  const u32 totalAll = totCnt[bc];

  if (totalAll == 0u) {
    for (int r = tid; r < MAXDET; r += 512) {
      keptScore[bc * MAXDET + r] = -INFINITY;
      keptN[bc * MAXDET + r] = 0;
    }
    if (tid == 0) keptCount[bc] = 0;
    return;
  }
  const u32 target = totalAll < TARGETK ? totalAll : TARGETK;
  if (specRaw > SPECCAP || specRaw < target) {  // speculation failed: exact path
    slow_path(boxes, cls, bc, keptScore, keptN, keptCount, ghist, gtail, smem);
    return;
  }
  const u32 specCount = specRaw;

  // Load bucket + build 512-ULP histogram.
  const u64* bk = bucketKeys + (size_t)bc * SPECCAP;
  for (int i = tid; i < (int)specCount; i += 512) side[i] = bk[i];
  for (int i = tid; i < NHB; i += 512) hist[i] = 0u;
  if (tid == 0) { s_cnt = 0u; s_kept = 0; }
  __syncthreads();
  for (int i = tid; i < (int)specCount; i += 512) {
    u32 bits = (u32)(side[i] >> 32);
    u32 h = (bits >> 9) - HB0;
    if (h > NHB - 1) h = NHB - 1;
    atomicAdd(&hist[h], 1u);
  }
  __syncthreads();

  suffix_fast<NHB, 512>(hist, target, wsum, selB);
  const u32 F0 = selB[0];
  const u32 selCount = selB[1];
  if (selCount > CAP) {  // tie pile-up beyond sort capacity
    __syncthreads();
    slow_path(boxes, cls, bc, keptScore, keptN, keptCount, ghist, gtail, smem);
    return;
  }

  // Compact selected (h >= F0) into keys, wave-aggregated.
  const int iters = (int)((specCount + 511u) >> 9);
  for (int it2 = 0; it2 < iters; ++it2) {
    u32 idx = (u32)it2 * 512u + (u32)tid;
    bool act = idx < specCount;
    u64 key = act ? side[idx] : 0ull;
    u32 bits = (u32)(key >> 32);
    u32 h = (bits >> 9) - HB0;
    if (h > NHB - 1) h = NHB - 1;
    bool sel = act && (h >= F0);
    u64 ms = __ballot(sel);
    if (ms) {
      u32 bs;
      if (lane == 0) bs = atomicAdd(&s_cnt, (u32)__popcll(ms));
      bs = __shfl(bs, 0);
      if (sel) keys[bs + (u32)__popcll(ms & lmask)] = key;
    }
  }
  __syncthreads();
  for (int i = (int)selCount + tid; i < CAP; i += 512) keys[i] = 0ull;
  __syncthreads();

  bitonic_sort<512>(keys, CAP, tid);

  // Gather candidate boxes (side region dead; candbox/carea alias it).
  for (int i = tid; i < (int)selCount; i += 512) {
    int pos = CAP - 1 - i;
    u32 n = ~((u32)keys[pos]);
    float4 bb = ((const float4*)boxes)[(size_t)b * NBOX + n];
    candbox[pos] = bb;
    carea[pos] = __fmul_rn(__fsub_rn(bb.z, bb.x), __fsub_rn(bb.w, bb.y));
  }
  __syncthreads();

  // Tile-parallel greedy walk (round-13 structure, frozen).
  const u32 ntile = (selCount + 63u) >> 6;
  for (u32 t = 0; t < ntile; ++t) {
    const int kept0 = s_kept;
    if (kept0 >= MAXDET) break;
    const u32 r = t * 64u + (u32)lane;
    const bool valid = r < selCount;
    const int si = valid ? (CAP - 1 - (int)r) : (CAP - 1);
    float4 mybox = candbox[si];
    float marea = carea[si];
    bool sup = false;
    for (int k = w; k < kept0; k += WWAVES) {
      float4 kb = keptbox[k];
      if (iou_sup_fast(kb.x, kb.y, kb.z, kb.w, karea[k],
                       mybox.x, mybox.y, mybox.z, mybox.w, marea))
        sup = true;
    }
    u64 bal = __ballot(sup);
    if (lane == 0) supW[w] = bal;
    u64 mw = 0ull;
    const int ebase = w * 8;
#pragma unroll
    for (int ee = 0; ee < 8; ++ee) {
      const int e = ebase + ee;
      int ei = CAP - 1 - (int)(t * 64u) - e;
      float4 eb = candbox[ei];
      if (e < lane && iou_sup_fast(eb.x, eb.y, eb.z, eb.w, carea[ei],
                                   mybox.x, mybox.y, mybox.z, mybox.w, marea))
        mw |= 1ull << e;
    }
    mpart[w][lane] = mw;
    __syncthreads();
    if (w == 0) {
      u64 prior = 0ull, m = 0ull;
#pragma unroll
      for (int ww = 0; ww < WWAVES; ++ww) {
        prior |= supW[ww];
        m |= mpart[ww][lane];
      }
      u64 remaining = __ballot(valid) & ~prior;
      u64 keptmask = 0ull;
      const int room = MAXDET - kept0;
      while (remaining != 0ull && (int)__popcll(keptmask) < room) {
        int j = __ffsll((long long)remaining) - 1;
        keptmask |= 1ull << j;
        remaining &= ~(1ull << j);
        u64 supj = __ballot(((m >> j) & 1ull) != 0ull);
        remaining &= ~supj;
      }
      if ((keptmask >> lane) & 1ull) {
        int pos = kept0 + (int)__popcll(keptmask & lmask);
        u64 mykey = keys[CAP - 1 - (int)r];
        keptbox[pos] = mybox;
        karea[pos] = marea;
        kn[pos] = (int)(~((u32)mykey));
        ksc[pos] = __uint_as_float((u32)(mykey >> 32));
      }
      if (lane == 0) s_kept = kept0 + (int)__popcll(keptmask);
    }
    __syncthreads();
  }

  const int kept = s_kept;
  const bool exhausted = (kept < MAXDET && selCount < totalAll);
  if (exhausted) {  // prefix exhausted: redo exactly, inline
    __syncthreads();
    slow_path(boxes, cls, bc, keptScore, keptN, keptCount, ghist, gtail, smem);
    return;
  }
  for (int rr = tid; rr < MAXDET; rr += 512) {
    keptScore[bc * MAXDET + rr] = (rr < kept) ? ksc[rr] : -INFINITY;
    keptN[bc * MAXDET + rr] = (rr < kept) ? kn[rr] : 0;
  }
  if (tid == 0) keptCount[bc] = kept;
  for (int rr = tid; rr < kept; rr += 512) {  // top-k histogram contribution
    float s = ksc[rr];
    if (s > SPEC_THRF) {
      u32 h = (__float_as_uint(s) >> 9) - HB0;
      if (h > NHB - 1) h = NHB - 1;
      atomicAdd(&ghist[b * NHB + h], 1u);
    } else {
      atomicAdd(&gtail[b], 1u);
    }
  }
}

// Top-k + outputs: suffix-select from prebuilt per-batch hist -> compact scan ->
// bitonic-512 (exact lax.top_k ties) -> emit. Fallback: exact serial 80-way merge.
__global__ __launch_bounds__(256) void k_osort(const float* __restrict__ boxes,
                                               const float* __restrict__ rel,
                                               const float* __restrict__ keptScore,
                                               const int* __restrict__ keptN,
                                               const u32* __restrict__ ghist,
                                               const u32* __restrict__ gtail,
                                               float* __restrict__ out) {
  __shared__ u64 keys[1024];
  __shared__ u32 wsum[4], selB[4];
  __shared__ u32 s_cnt;
  const int tid = threadIdx.x;
  const int lane = tid & 63;
  const u64 lmask = (1ull << lane) - 1ull;
  const int b = blockIdx.x;
  const float4* ks4 = (const float4*)(keptScore + (size_t)b * NTOT);

  if (tid == 0) s_cnt = 0u;
  suffix_fast<NHB, 256>(ghist + (size_t)b * NHB, (u32)MAXDET, wsum, selB);
  const u32 specTotal = selB[3];
  const u32 totalAll = specTotal + gtail[b];
  const u32 target = totalAll < (u32)MAXDET ? totalAll : (u32)MAXDET;
  const u32 F0 = selB[0];
  const u32 selSpec = selB[1];
  const bool fast = (totalAll != 0u) && (specTotal >= target) && (selSpec <= (u32)CAP);
  int SZ = CAP;

  if (totalAll != 0u) {
    if (fast) {
      for (int base = 0; base < NTOT / 4; base += 2048) {
        float4 v[8];
#pragma unroll
        for (int p = 0; p < 8; ++p) {
          int q = base + tid + (p << 8);
          if (q < NTOT / 4) v[p] = ks4[q];
        }
#pragma unroll
        for (int p = 0; p < 8; ++p) {
          int q = base + tid + (p << 8);
          if (q < NTOT / 4) {
            float vv[4] = {v[p].x, v[p].y, v[p].z, v[p].w};
#pragma unroll
            for (int e = 0; e < 4; ++e) {
              float s = vv[e];
              bool sel = false;
              u32 bits = 0;
              if (s > SPEC_THRF) {
                bits = __float_as_uint(s);
                u32 h = (bits >> 9) - HB0;
                if (h > NHB - 1) h = NHB - 1;
                sel = (h >= F0);
              }
              u64 ms = __ballot(sel);
              if (ms) {
                u32 bs;
                if (lane == 0) bs = atomicAdd(&s_cnt, (u32)__popcll(ms));
                bs = __shfl(bs, 0);
                if (sel)
                  keys[bs + (u32)__popcll(ms & lmask)] =
                      ((u64)bits << 32) | (~(u32)(q * 4 + e));
              }
            }
          }
        }
      }
      __syncthreads();
      for (int i = (int)selSpec + tid; i < CAP; i += 256) keys[i] = 0ull;
      __syncthreads();
      bitonic_sort<256>(keys, CAP, tid);
      SZ = CAP;
    } else {
      // Exact fallback: serial 80-way merge of the sorted per-class lists.
      if (tid < 64) {
        const int c0 = lane, c1 = 64 + lane;
        const bool has1 = (c1 < NCLS);
        const float* ls0 = keptScore + ((size_t)b * NCLS + c0) * MAXDET;
        const float* ls1 = keptScore + ((size_t)b * NCLS + (has1 ? c1 : c0)) * MAXDET;
        int h0 = 0, h1 = 0;
        float v0 = ls0[0], w0v = ls0[1];
        float v1 = has1 ? ls1[0] : -INFINITY;
        float w1v = has1 ? ls1[1] : -INFINITY;
        for (int r = 0; r < (int)target; ++r) {
          float bs; int bcl;
          if (has1 && v1 > v0) { bs = v1; bcl = c1; } else { bs = v0; bcl = c0; }
#pragma unroll
          for (int off = 32; off > 0; off >>= 1) {
            float os = __shfl_xor(bs, off);
            int oc = __shfl_xor(bcl, off);
            if (os > bs || (os == bs && oc < bcl)) { bs = os; bcl = oc; }
          }
          if (bcl == c0) {
            keys[1023 - r] = ((u64)__float_as_uint(bs) << 32) | (~(u32)(c0 * MAXDET + h0));
            ++h0; v0 = w0v; w0v = (h0 + 1 < MAXDET) ? ls0[h0 + 1] : -INFINITY;
          } else if (has1 && bcl == c1) {
            keys[1023 - r] = ((u64)__float_as_uint(bs) << 32) | (~(u32)(c1 * MAXDET + h1));
            ++h1; v1 = w1v; w1v = (h1 + 1 < MAXDET) ? ls1[h1 + 1] : -INFINITY;
          }
        }
      }
      __syncthreads();
      SZ = 1024;
    }
  }

  for (int r = tid; r < MAXDET; r += 256) {
    const bool valid = (u32)r < target;
    float s = -1.0f, pm = -1.0f, pl = -1.0f, cl = -1.0f;
    float4 ob; ob.x = ob.y = ob.z = ob.w = -1.0f;
    if (valid) {
      u64 key = keys[SZ - 1 - r];
      u32 fp = ~((u32)key);
      int c = (int)(fp / MAXDET);
      int slot = (int)(fp - (u32)c * MAXDET);
      int n = keptN[((size_t)b * NCLS + c) * MAXDET + slot];
      s = __uint_as_float((u32)(key >> 32));
      cl = (float)c;
      size_t nb = (size_t)b * NBOX + (u32)n;
      ob = ((const float4*)boxes)[nb];
      const float* rp = rel + nb * NREL;
      float vr[NREL];
#pragma unroll
      for (int p = 0; p < NREL; ++p) vr[p] = rp[p];  // all loads in flight
      float best = vr[0]; int bi = 0;
#pragma unroll
      for (int p = 1; p < NREL; ++p) { if (vr[p] > best) { best = vr[p]; bi = p; } }
      pm = best; pl = (float)bi;
    }
    ((float4*)out)[(size_t)b * MAXDET + r] = ob;
    const int sbase = NBATCH * MAXDET * 4;
    out[sbase + b * MAXDET + r] = s;
    out[sbase + NBATCH * MAXDET + b * MAXDET + r] = cl;
    out[sbase + 2 * NBATCH * MAXDET + b * MAXDET + r] = pm;
    out[sbase + 3 * NBATCH * MAXDET + b * MAXDET + r] = pl;
  }
}

extern "C" void kernel_launch(void* const* d_in, const int* in_sizes, int n_in,
                              void* d_out, int out_size, void* d_ws, size_t ws_size,
                              hipStream_t stream) {
  (void)in_sizes; (void)n_in; (void)out_size; (void)ws_size;
  const float* boxes = (const float*)d_in[0];
  const float* cls   = (const float*)d_in[1];
  const float* rel   = (const float*)d_in[2];
  float* out = (float*)d_out;
  char* ws = (char*)d_ws;

  const size_t NP = NBATCH * NCLS;  // 640 problems
  size_t off = 0;
  const size_t oKeptScore = off; off += NP * MAXDET * 4;
  const size_t oKeptN     = off; off += NP * MAXDET * 4;
  const size_t oKeptCount = off; off += NP * 4;
  const size_t oBucketCnt = off; off += NP * 4;
  const size_t oTotCnt    = off; off += NP * 4;
  const size_t oGtail     = off; off += NBATCH * 4;
  off = (off + 7) & ~(size_t)7;
  const size_t oGhist     = off; off += (size_t)NBATCH * NHB * 4;
  off = (off + 7) & ~(size_t)7;
  const size_t oBucketKeys = off; off += NP * SPECCAP * 8;        // 13.1 MB

  float* keptScore = (float*)(ws + oKeptScore);
  int* keptN = (int*)(ws + oKeptN);
  int* keptCount = (int*)(ws + oKeptCount);
  u32* bucketCnt = (u32*)(ws + oBucketCnt);
  u32* totCnt = (u32*)(ws + oTotCnt);
  u32* gtail = (u32*)(ws + oGtail);
  u32* ghist = (u32*)(ws + oGhist);
  u64* bucketKeys = (u64*)(ws + oBucketKeys);

  k_init<<<NBATCH, 256, 0, stream>>>(ghist, gtail, bucketCnt, totCnt);
  k_gather<<<dim3((NBOX + 63) / 64, NBATCH), 256, 0, stream>>>(cls, bucketKeys,
                                                               bucketCnt, totCnt);
  k_nms<<<NP, 512, 0, stream>>>(boxes, cls, bucketKeys, bucketCnt, totCnt,
                                keptScore, keptN, keptCount, ghist, gtail);
  k_osort<<<NBATCH, 256, 0, stream>>>(boxes, rel, keptScore, keptN, ghist, gtail, out);
}

// Round 16
// 142.541 us; speedup vs baseline: 3.6959x; 2.9815x over previous
//
#include <hip/hip_runtime.h>
#include <hip/hip_bf16.h>
#include <math.h>

#define NBATCH 8
#define NBOX   20000
#define NCLS   80
#define NREL   51
#define MAXDET 300
#define NTOT   (NCLS * MAXDET)      // 24000
#define CAP    512
#define SPECCAP 2560
#define NHB    3584                 // 512-ULP buckets over (0.9, 1.0]
#define HB0    (0x3F666666u >> 9)   // bucket base = bits(0.9f) >> 9
#define TARGETK 480u
#define SCORE_THR 0.05f
#define SPEC_THRF 0.9f
#define WWAVES 8
#define GBOX   128                  // boxes per gather block
#define KCAP   48                   // staged keys per class per block (10.5 sigma)

typedef unsigned long long u64;
typedef unsigned int u32;

// IoU > 0.5, explicit IEEE div (slow path only).
__device__ __forceinline__ bool iou_sup(float ax1, float ay1, float ax2, float ay2, float aarea,
                                        float bx1, float by1, float bx2, float by2, float barea) {
  float ix1 = fmaxf(ax1, bx1);
  float iy1 = fmaxf(ay1, by1);
  float ix2 = fminf(ax2, bx2);
  float iy2 = fminf(ay2, by2);
  float dw = fmaxf(__fsub_rn(ix2, ix1), 0.0f);
  float dh = fmaxf(__fsub_rn(iy2, iy1), 0.0f);
  float inter = __fmul_rn(dw, dh);
  float uni = __fsub_rn(__fadd_rn(aarea, barea), inter);
  if (!(uni > 0.0f)) return false;
  return __fdiv_rn(inter, uni) > 0.5f;
}

__device__ __forceinline__ bool iou_gt_half(float ax1, float ay1, float ax2, float ay2,
                                            float bx1, float by1, float bx2, float by2) {
  float aa = __fmul_rn(__fsub_rn(ax2, ax1), __fsub_rn(ay2, ay1));
  float ab = __fmul_rn(__fsub_rn(bx2, bx1), __fsub_rn(by2, by1));
  return iou_sup(ax1, ay1, ax2, ay2, aa, bx1, by1, bx2, by2, ab);
}

// Bit-exact div-free IoU>0.5 in PURE f32 (proof in round-9 notes).
__device__ __forceinline__ bool iou_sup_fast(float ax1, float ay1, float ax2, float ay2,
                                             float aarea, float bx1, float by1, float bx2,
                                             float by2, float barea) {
  float ix1 = fmaxf(ax1, bx1);
  float iy1 = fmaxf(ay1, by1);
  float ix2 = fminf(ax2, bx2);
  float iy2 = fminf(ay2, by2);
  float dw = fmaxf(__fsub_rn(ix2, ix1), 0.0f);
  float dh = fmaxf(__fsub_rn(iy2, iy1), 0.0f);
  float inter = __fmul_rn(dw, dh);
  float uni = __fsub_rn(__fadd_rn(aarea, barea), inter);
  return (uni > 0.0f) && (inter > __fmul_rn(0.5f, uni));
}

#define CEXR(x, y, asc) { bool sw_ = (asc) ? ((x) > (y)) : ((x) < (y)); \
                          if (sw_) { u64 t_ = (x); (x) = (y); (y) = t_; } }

// Bitonic sort ascending over SZ u64 keys in LDS.
template <int THREADS>
__device__ __forceinline__ void bitonic_sort(u64* keys, int SZ, int tid) {
  for (int k = 2; k <= SZ; k <<= 1) {
    for (int j = k >> 1; j >= 4; j >>= 1) {
      for (int v = tid; v < (SZ >> 1); v += THREADS) {
        int i = ((v & ~(j - 1)) << 1) | (v & (j - 1));
        int p = i | j;
        bool asc = ((i & k) == 0);
        u64 a = keys[i], b = keys[p];
        bool sw = asc ? (a > b) : (a < b);
        if (sw) { keys[i] = b; keys[p] = a; }
      }
      __syncthreads();
    }
    if (tid < (SZ >> 2)) {
      ulonglong2* k2 = (ulonglong2*)keys;
      ulonglong2 lo = k2[tid * 2], hi = k2[tid * 2 + 1];
      u64 a = lo.x, b = lo.y, c = hi.x, d = hi.y;
      int i0 = tid << 2;
      if (k == 2) {
        CEXR(a, b, true); CEXR(c, d, false);
      } else {
        bool asc = ((i0 & k) == 0);
        CEXR(a, c, asc); CEXR(b, d, asc);  // j = 2
        CEXR(a, b, asc); CEXR(c, d, asc);  // j = 1
      }
      lo.x = a; lo.y = b; hi.x = c; hi.y = d;
      k2[tid * 2] = lo; k2[tid * 2 + 1] = hi;
    }
    __syncthreads();
  }
}

// Barrier-light suffix select over NB buckets: minimal suffix >= min(total, cap).
// sout: [0]=bucket [1]=sel [2]=above [3]=total.
template <int NB, int THREADS>
__device__ __forceinline__ void suffix_fast(const u32* hist, u32 cap, u32* wsum, u32* sout) {
  const int tid = threadIdx.x, lane = tid & 63, w = tid >> 6;
  const int NW = THREADS / 64;
  const int G = NB / THREADS;
  u32 v = 0;
  const int hb = tid * G;
#pragma unroll
  for (int t = 0; t < G; ++t) v += hist[hb + t];
  u32 s = v;
#pragma unroll
  for (int off = 1; off < 64; off <<= 1) {
    u32 t2 = __shfl_down(s, off);
    if (lane + off < 64) s += t2;
  }
  if (lane == 0) wsum[w] = s;
  __syncthreads();
  u32 total = 0;
#pragma unroll
  for (int ww = 0; ww < NW; ++ww) total += wsum[ww];
  u32 after = 0;
#pragma unroll
  for (int ww = 1; ww < NW; ++ww) if (ww > w) after += wsum[ww];
  u32 inc = s + after;
  u32 exc = inc - v;
  if (tid == 0) {
    sout[3] = total;
    if (total == 0u) { sout[0] = 0u; sout[1] = 0u; sout[2] = 0u; }
  }
  u32 target = total < cap ? total : cap;
  if (total != 0u && inc >= target && exc < target) {  // exactly one thread
    u32 acc = exc;
    for (int u = hb + G - 1; u >= hb; --u) {
      acc += hist[u];
      if (acc >= target) { sout[0] = (u32)u; sout[1] = acc; sout[2] = acc - hist[u]; break; }
    }
  }
  __syncthreads();
}

// Zero all per-launch scratch (counters + per-batch top-k histogram).
__global__ __launch_bounds__(256) void k_init(u32* __restrict__ ghist,
                                              u32* __restrict__ gtail,
                                              u32* __restrict__ bucketCnt,
                                              u32* __restrict__ totCnt) {
  const int b = blockIdx.x;
  const int tid = threadIdx.x;
  for (int i = tid; i < NHB; i += 256) ghist[b * NHB + i] = 0u;
  if (tid == 0) gtail[b] = 0u;
  for (int i = tid; i < NCLS; i += 256) {
    bucketCnt[b * NCLS + i] = 0u;
    totCnt[b * NCLS + i] = 0u;
  }
}

// 128 boxes/block: transpose tiles -> per-class LDS staging (exclusive wave owner,
// NO atomics) -> ONE parallel global atomic per class (80 concurrent round-trips,
// no serial chain) -> contiguous copy to buckets. Overflow (>KCAP staged) forces
// bucketCnt > SPECCAP -> exact slow path in k_nms. Bucket order nondeterministic;
// count-based selection + full sort canonicalize -> bit-exact.
__global__ __launch_bounds__(256) void k_gather(const float* __restrict__ cls,
                                                u64* __restrict__ bucketKeys,
                                                u32* __restrict__ bucketCnt,
                                                u32* __restrict__ totCnt) {
  __shared__ float tile[NCLS * 65];          // 20800 B
  __shared__ u64 stKeys[NCLS][KCAP];         // 30720 B
  __shared__ u32 stCnt[NCLS], totC[NCLS], sBase[NCLS], stOvf[NCLS];
  const int tid = threadIdx.x;
  const int lane = tid & 63;
  const int w = tid >> 6;
  const u64 lmask = (1ull << lane) - 1ull;
  const int b = blockIdx.y;
  const int g0 = blockIdx.x * GBOX;

  for (int i = tid; i < NCLS; i += 256) { stCnt[i] = 0u; totC[i] = 0u; stOvf[i] = 0u; }
  __syncthreads();

  for (int half = 0; half < 2; ++half) {
    const int n0 = g0 + half * 64;
    const int rows = (NBOX - n0) < 64 ? (NBOX - n0) : 64;
    if (rows > 0) {
      const float4* src4 = (const float4*)(cls + ((size_t)b * NBOX + n0) * NCLS);
      const int nq = rows * (NCLS / 4);
      for (int i = tid; i < nq; i += 256) {
        int rr = i / (NCLS / 4);
        int c4 = i - rr * (NCLS / 4);
        float4 v = src4[i];
        tile[(c4 * 4 + 0) * 65 + rr] = v.x;
        tile[(c4 * 4 + 1) * 65 + rr] = v.y;
        tile[(c4 * 4 + 2) * 65 + rr] = v.z;
        tile[(c4 * 4 + 3) * 65 + rr] = v.w;
      }
    }
    __syncthreads();
    if (rows > 0) {
      for (int c = w; c < NCLS; c += 4) {   // wave w exclusively owns class c
        float s = (lane < rows) ? tile[c * 65 + lane] : 0.0f;
        u64 am = __ballot(s > SCORE_THR);
        u64 sm = __ballot(s > SPEC_THRF);
        if (lane == 0 && am) totC[c] += (u32)__popcll(am);
        if (sm) {
          u32 base = stCnt[c];              // uniform read (owner wave, lockstep)
          u32 cnt = (u32)__popcll(sm);
          if (s > SPEC_THRF) {
            u32 pos = base + (u32)__popcll(sm & lmask);
            if (pos < KCAP)
              stKeys[c][pos] = ((u64)__float_as_uint(s) << 32) | (~(u32)(n0 + lane));
          }
          if (lane == 0) {
            u32 nc = base + cnt;
            if (nc > KCAP) { stOvf[c] = 1u; nc = KCAP; }
            stCnt[c] = nc;
          }
        }
      }
    }
    __syncthreads();   // tile reuse / staging visibility
  }

  // ONE atomic per class, issued by 80 threads in parallel (latency overlapped).
  if (tid < NCLS) {
    u32 tc = totC[tid];
    if (tc) atomicAdd(&totCnt[b * NCLS + tid], tc);
    u32 cnt = stCnt[tid];
    u32 base = 0;
    if (cnt) base = atomicAdd(&bucketCnt[b * NCLS + tid], cnt);
    if (stOvf[tid]) atomicAdd(&bucketCnt[b * NCLS + tid], (u32)SPECCAP + 1u);
    sBase[tid] = base;
  }
  __syncthreads();

  // Contiguous copy staged -> global buckets.
  for (int c = w; c < NCLS; c += 4) {
    u32 cnt = stCnt[c];
    u32 base = sBase[c];
    u64* dst = bucketKeys + (size_t)(b * NCLS + c) * SPECCAP;
    for (u32 i = lane; i < cnt; i += 64) {
      u32 pos = base + i;
      if (pos < SPECCAP) dst[pos] = stKeys[c][i];
    }
  }
}

// Exact reference-style greedy NMS (slow path), 512-thread, inline from k_nms.
__device__ void slow_path(const float* __restrict__ boxes,
                          const float* __restrict__ cls, int bc,
                          float* __restrict__ keptScore, int* __restrict__ keptN,
                          int* __restrict__ keptCount,
                          u32* __restrict__ ghist, u32* __restrict__ gtail,
                          char* smem) {
  u32* sup = (u32*)smem;                       // [(NBOX+31)/32] u32 @0
  u64* red = (u64*)(smem + 2560);              // [512] u64 @2560
  float4* sbx = (float4*)(smem + 6656);
  int* s_kept = (int*)(smem + 6672);
  const int tid = threadIdx.x;
  const int b = bc / NCLS, c = bc % NCLS;
  const float* col = cls + (size_t)b * NBOX * NCLS + c;

  for (int i = tid; i < (NBOX + 31) / 32; i += 512) sup[i] = 0u;
  if (tid == 0) *s_kept = 0;
  __syncthreads();
  for (int it = 0; it < MAXDET; ++it) {
    u64 best = 0ull;
    for (int n = tid; n < NBOX; n += 512) {
      if ((sup[n >> 5] >> (n & 31)) & 1u) continue;
      float s = col[(size_t)n * NCLS];
      if (s > SCORE_THR) {
        u64 key = ((u64)__float_as_uint(s) << 32) | (~(u32)n);
        if (key > best) best = key;
      }
    }
    red[tid] = best;
    __syncthreads();
    for (int off = 256; off > 0; off >>= 1) {
      if (tid < off) { u64 o = red[tid + off]; if (o > red[tid]) red[tid] = o; }
      __syncthreads();
    }
    u64 win = red[0];
    if (win == 0ull) break;
    u32 nw = ~((u32)win);
    if (tid == 0) {
      int k = *s_kept;
      keptScore[bc * MAXDET + k] = __uint_as_float((u32)(win >> 32));
      keptN[bc * MAXDET + k] = (int)nw;
      *s_kept = k + 1;
      *sbx = ((const float4*)boxes)[(size_t)b * NBOX + nw];
    }
    __syncthreads();
    float4 bx = *sbx;
    for (int n = tid; n < NBOX; n += 512) {
      float4 cb = ((const float4*)boxes)[(size_t)b * NBOX + n];
      if (iou_gt_half(bx.x, bx.y, bx.z, bx.w, cb.x, cb.y, cb.z, cb.w))
        atomicOr(&sup[n >> 5], 1u << (n & 31));
    }
    if (tid == 0) atomicOr(&sup[nw >> 5], 1u << (nw & 31));
    __syncthreads();
  }
  __syncthreads();
  const int kept = *s_kept;
  for (int r = kept + tid; r < MAXDET; r += 512) {
    keptScore[bc * MAXDET + r] = -INFINITY;
    keptN[bc * MAXDET + r] = 0;
  }
  for (int rr = tid; rr < kept; rr += 512) {
    float s = keptScore[bc * MAXDET + rr];
    if (s > SPEC_THRF) {
      u32 h = (__float_as_uint(s) >> 9) - HB0;
      if (h > NHB - 1) h = NHB - 1;
      atomicAdd(&ghist[b * NHB + h], 1u);
    } else {
      atomicAdd(&gtail[b], 1u);
    }
  }
  if (tid == 0) keptCount[bc] = kept;
}

// Fused per-(b,c) kernel: bucket load -> LDS histogram select -> compact ->
// bitonic-512 -> round-13 tile-parallel greedy walk (frozen). Slow path inline.
__global__ __launch_bounds__(512) void k_nms(const float* __restrict__ boxes,
                                             const float* __restrict__ cls,
                                             const u64* __restrict__ bucketKeys,
                                             const u32* __restrict__ bucketCnt,
                                             const u32* __restrict__ totCnt,
                                             float* __restrict__ keptScore,
                                             int* __restrict__ keptN,
                                             int* __restrict__ keptCount,
                                             u32* __restrict__ ghist,
                                             u32* __restrict__ gtail) {
  __shared__ __align__(16) char smem[38912];
  u64* side = (u64*)smem;
  u32* hist = (u32*)(smem + 20480);
  u64* keys = (u64*)(smem + 34816);
  float4* candbox = (float4*)smem;
  float* carea = (float*)(smem + 8192);
  float4* keptbox = (float4*)(smem + 10240);
  float* karea = (float*)(smem + 15040);
  int* kn = (int*)(smem + 16240);
  float* ksc = (float*)(smem + 17440);
  __shared__ u32 wsum[WWAVES], selB[4];
  __shared__ u32 s_cnt;
  __shared__ u64 supW[WWAVES];
  __shared__ u64 mpart[WWAVES][64];
  __shared__ int s_kept;

  const int tid = threadIdx.x;
  const int lane = tid & 63;
  const int w = tid >> 6;
  const u64 lmask = (1ull << lane) - 1ull;
  const int bc = blockIdx.x;
  const int b = bc / NCLS;

  const u32 specRaw = bucketCnt[bc];
  const u32 totalAll = totCnt[bc];

  if (totalAll == 0u) {
    for (int r = tid; r < MAXDET; r += 512) {
      keptScore[bc * MAXDET + r] = -INFINITY;
      keptN[bc * MAXDET + r] = 0;
    }
    if (tid == 0) keptCount[bc] = 0;
    return;
  }
  const u32 target = totalAll < TARGETK ? totalAll : TARGETK;
  if (specRaw > SPECCAP || specRaw < target) {
    slow_path(boxes, cls, bc, keptScore, keptN, keptCount, ghist, gtail, smem);
    return;
  }
  const u32 specCount = specRaw;

  const u64* bk = bucketKeys + (size_t)bc * SPECCAP;
  for (int i = tid; i < (int)specCount; i += 512) side[i] = bk[i];
  for (int i = tid; i < NHB; i += 512) hist[i] = 0u;
  if (tid == 0) { s_cnt = 0u; s_kept = 0; }
  __syncthreads();
  for (int i = tid; i < (int)specCount; i += 512) {
    u32 bits = (u32)(side[i] >> 32);
    u32 h = (bits >> 9) - HB0;
    if (h > NHB - 1) h = NHB - 1;
    atomicAdd(&hist[h], 1u);
  }
  __syncthreads();

  suffix_fast<NHB, 512>(hist, target, wsum, selB);
  const u32 F0 = selB[0];
  const u32 selCount = selB[1];
  if (selCount > CAP) {
    __syncthreads();
    slow_path(boxes, cls, bc, keptScore, keptN, keptCount, ghist, gtail, smem);
    return;
  }

  const int iters = (int)((specCount + 511u) >> 9);
  for (int it2 = 0; it2 < iters; ++it2) {
    u32 idx = (u32)it2 * 512u + (u32)tid;
    bool act = idx < specCount;
    u64 key = act ? side[idx] : 0ull;
    u32 bits = (u32)(key >> 32);
    u32 h = (bits >> 9) - HB0;
    if (h > NHB - 1) h = NHB - 1;
    bool sel = act && (h >= F0);
    u64 ms = __ballot(sel);
    if (ms) {
      u32 bs;
      if (lane == 0) bs = atomicAdd(&s_cnt, (u32)__popcll(ms));
      bs = __shfl(bs, 0);
      if (sel) keys[bs + (u32)__popcll(ms & lmask)] = key;
    }
  }
  __syncthreads();
  for (int i = (int)selCount + tid; i < CAP; i += 512) keys[i] = 0ull;
  __syncthreads();

  bitonic_sort<512>(keys, CAP, tid);

  for (int i = tid; i < (int)selCount; i += 512) {
    int pos = CAP - 1 - i;
    u32 n = ~((u32)keys[pos]);
    float4 bb = ((const float4*)boxes)[(size_t)b * NBOX + n];
    candbox[pos] = bb;
    carea[pos] = __fmul_rn(__fsub_rn(bb.z, bb.x), __fsub_rn(bb.w, bb.y));
  }
  __syncthreads();

  const u32 ntile = (selCount + 63u) >> 6;
  for (u32 t = 0; t < ntile; ++t) {
    const int kept0 = s_kept;
    if (kept0 >= MAXDET) break;
    const u32 r = t * 64u + (u32)lane;
    const bool valid = r < selCount;
    const int si = valid ? (CAP - 1 - (int)r) : (CAP - 1);
    float4 mybox = candbox[si];
    float marea = carea[si];
    bool sup = false;
    for (int k = w; k < kept0; k += WWAVES) {
      float4 kb = keptbox[k];
      if (iou_sup_fast(kb.x, kb.y, kb.z, kb.w, karea[k],
                       mybox.x, mybox.y, mybox.z, mybox.w, marea))
        sup = true;
    }
    u64 bal = __ballot(sup);
    if (lane == 0) supW[w] = bal;
    u64 mw = 0ull;
    const int ebase = w * 8;
#pragma unroll
    for (int ee = 0; ee < 8; ++ee) {
      const int e = ebase + ee;
      int ei = CAP - 1 - (int)(t * 64u) - e;
      float4 eb = candbox[ei];
      if (e < lane && iou_sup_fast(eb.x, eb.y, eb.z, eb.w, carea[ei],
                                   mybox.x, mybox.y, mybox.z, mybox.w, marea))
        mw |= 1ull << e;
    }
    mpart[w][lane] = mw;
    __syncthreads();
    if (w == 0) {
      u64 prior = 0ull, m = 0ull;
#pragma unroll
      for (int ww = 0; ww < WWAVES; ++ww) {
        prior |= supW[ww];
        m |= mpart[ww][lane];
      }
      u64 remaining = __ballot(valid) & ~prior;
      u64 keptmask = 0ull;
      const int room = MAXDET - kept0;
      while (remaining != 0ull && (int)__popcll(keptmask) < room) {
        int j = __ffsll((long long)remaining) - 1;
        keptmask |= 1ull << j;
        remaining &= ~(1ull << j);
        u64 supj = __ballot(((m >> j) & 1ull) != 0ull);
        remaining &= ~supj;
      }
      if ((keptmask >> lane) & 1ull) {
        int pos = kept0 + (int)__popcll(keptmask & lmask);
        u64 mykey = keys[CAP - 1 - (int)r];
        keptbox[pos] = mybox;
        karea[pos] = marea;
        kn[pos] = (int)(~((u32)mykey));
        ksc[pos] = __uint_as_float((u32)(mykey >> 32));
      }
      if (lane == 0) s_kept = kept0 + (int)__popcll(keptmask);
    }
    __syncthreads();
  }

  const int kept = s_kept;
  const bool exhausted = (kept < MAXDET && selCount < totalAll);
  if (exhausted) {
    __syncthreads();
    slow_path(boxes, cls, bc, keptScore, keptN, keptCount, ghist, gtail, smem);
    return;
  }
  for (int rr = tid; rr < MAXDET; rr += 512) {
    keptScore[bc * MAXDET + rr] = (rr < kept) ? ksc[rr] : -INFINITY;
    keptN[bc * MAXDET + rr] = (rr < kept) ? kn[rr] : 0;
  }
  if (tid == 0) keptCount[bc] = kept;
  for (int rr = tid; rr < kept; rr += 512) {
    float s = ksc[rr];
    if (s > SPEC_THRF) {
      u32 h = (__float_as_uint(s) >> 9) - HB0;
      if (h > NHB - 1) h = NHB - 1;
      atomicAdd(&ghist[b * NHB + h], 1u);
    } else {
      atomicAdd(&gtail[b], 1u);
    }
  }
}

// Top-k + outputs (unchanged from round 15).
__global__ __launch_bounds__(256) void k_osort(const float* __restrict__ boxes,
                                               const float* __restrict__ rel,
                                               const float* __restrict__ keptScore,
                                               const int* __restrict__ keptN,
                                               const u32* __restrict__ ghist,
                                               const u32* __restrict__ gtail,
                                               float* __restrict__ out) {
  __shared__ u64 keys[1024];
  __shared__ u32 wsum[4], selB[4];
  __shared__ u32 s_cnt;
  const int tid = threadIdx.x;
  const int lane = tid & 63;
  const u64 lmask = (1ull << lane) - 1ull;
  const int b = blockIdx.x;
  const float4* ks4 = (const float4*)(keptScore + (size_t)b * NTOT);

  if (tid == 0) s_cnt = 0u;
  suffix_fast<NHB, 256>(ghist + (size_t)b * NHB, (u32)MAXDET, wsum, selB);
  const u32 specTotal = selB[3];
  const u32 totalAll = specTotal + gtail[b];
  const u32 target = totalAll < (u32)MAXDET ? totalAll : (u32)MAXDET;
  const u32 F0 = selB[0];
  const u32 selSpec = selB[1];
  const bool fast = (totalAll != 0u) && (specTotal >= target) && (selSpec <= (u32)CAP);
  int SZ = CAP;

  if (totalAll != 0u) {
    if (fast) {
      for (int base = 0; base < NTOT / 4; base += 2048) {
        float4 v[8];
#pragma unroll
        for (int p = 0; p < 8; ++p) {
          int q = base + tid + (p << 8);
          if (q < NTOT / 4) v[p] = ks4[q];
        }
#pragma unroll
        for (int p = 0; p < 8; ++p) {
          int q = base + tid + (p << 8);
          if (q < NTOT / 4) {
            float vv[4] = {v[p].x, v[p].y, v[p].z, v[p].w};
#pragma unroll
            for (int e = 0; e < 4; ++e) {
              float s = vv[e];
              bool sel = false;
              u32 bits = 0;
              if (s > SPEC_THRF) {
                bits = __float_as_uint(s);
                u32 h = (bits >> 9) - HB0;
                if (h > NHB - 1) h = NHB - 1;
                sel = (h >= F0);
              }
              u64 ms = __ballot(sel);
              if (ms) {
                u32 bs;
                if (lane == 0) bs = atomicAdd(&s_cnt, (u32)__popcll(ms));
                bs = __shfl(bs, 0);
                if (sel)
                  keys[bs + (u32)__popcll(ms & lmask)] =
                      ((u64)bits << 32) | (~(u32)(q * 4 + e));
              }
            }
          }
        }
      }
      __syncthreads();
      for (int i = (int)selSpec + tid; i < CAP; i += 256) keys[i] = 0ull;
      __syncthreads();
      bitonic_sort<256>(keys, CAP, tid);
      SZ = CAP;
    } else {
      if (tid < 64) {
        const int c0 = lane, c1 = 64 + lane;
        const bool has1 = (c1 < NCLS);
        const float* ls0 = keptScore + ((size_t)b * NCLS + c0) * MAXDET;
        const float* ls1 = keptScore + ((size_t)b * NCLS + (has1 ? c1 : c0)) * MAXDET;
        int h0 = 0, h1 = 0;
        float v0 = ls0[0], w0v = ls0[1];
        float v1 = has1 ? ls1[0] : -INFINITY;
        float w1v = has1 ? ls1[1] : -INFINITY;
        for (int r = 0; r < (int)target; ++r) {
          float bs; int bcl;
          if (has1 && v1 > v0) { bs = v1; bcl = c1; } else { bs = v0; bcl = c0; }
#pragma unroll
          for (int off = 32; off > 0; off >>= 1) {
            float os = __shfl_xor(bs, off);
            int oc = __shfl_xor(bcl, off);
            if (os > bs || (os == bs && oc < bcl)) { bs = os; bcl = oc; }
          }
          if (bcl == c0) {
            keys[1023 - r] = ((u64)__float_as_uint(bs) << 32) | (~(u32)(c0 * MAXDET + h0));
            ++h0; v0 = w0v; w0v = (h0 + 1 < MAXDET) ? ls0[h0 + 1] : -INFINITY;
          } else if (has1 && bcl == c1) {
            keys[1023 - r] = ((u64)__float_as_uint(bs) << 32) | (~(u32)(c1 * MAXDET + h1));
            ++h1; v1 = w1v; w1v = (h1 + 1 < MAXDET) ? ls1[h1 + 1] : -INFINITY;
          }
        }
      }
      __syncthreads();
      SZ = 1024;
    }
  }

  for (int r = tid; r < MAXDET; r += 256) {
    const bool valid = (u32)r < target;
    float s = -1.0f, pm = -1.0f, pl = -1.0f, cl = -1.0f;
    float4 ob; ob.x = ob.y = ob.z = ob.w = -1.0f;
    if (valid) {
      u64 key = keys[SZ - 1 - r];
      u32 fp = ~((u32)key);
      int c = (int)(fp / MAXDET);
      int slot = (int)(fp - (u32)c * MAXDET);
      int n = keptN[((size_t)b * NCLS + c) * MAXDET + slot];
      s = __uint_as_float((u32)(key >> 32));
      cl = (float)c;
      size_t nb = (size_t)b * NBOX + (u32)n;
      ob = ((const float4*)boxes)[nb];
      const float* rp = rel + nb * NREL;
      float vr[NREL];
#pragma unroll
      for (int p = 0; p < NREL; ++p) vr[p] = rp[p];
      float best = vr[0]; int bi = 0;
#pragma unroll
      for (int p = 1; p < NREL; ++p) { if (vr[p] > best) { best = vr[p]; bi = p; } }
      pm = best; pl = (float)bi;
    }
    ((float4*)out)[(size_t)b * MAXDET + r] = ob;
    const int sbase = NBATCH * MAXDET * 4;
    out[sbase + b * MAXDET + r] = s;
    out[sbase + NBATCH * MAXDET + b * MAXDET + r] = cl;
    out[sbase + 2 * NBATCH * MAXDET + b * MAXDET + r] = pm;
    out[sbase + 3 * NBATCH * MAXDET + b * MAXDET + r] = pl;
  }
}

extern "C" void kernel_launch(void* const* d_in, const int* in_sizes, int n_in,
                              void* d_out, int out_size, void* d_ws, size_t ws_size,
                              hipStream_t stream) {
  (void)in_sizes; (void)n_in; (void)out_size; (void)ws_size;
  const float* boxes = (const float*)d_in[0];
  const float* cls   = (const float*)d_in[1];
  const float* rel   = (const float*)d_in[2];
  float* out = (float*)d_out;
  char* ws = (char*)d_ws;

  const size_t NP = NBATCH * NCLS;  // 640 problems
  size_t off = 0;
  const size_t oKeptScore = off; off += NP * MAXDET * 4;
  const size_t oKeptN     = off; off += NP * MAXDET * 4;
  const size_t oKeptCount = off; off += NP * 4;
  const size_t oBucketCnt = off; off += NP * 4;
  const size_t oTotCnt    = off; off += NP * 4;
  const size_t oGtail     = off; off += NBATCH * 4;
  off = (off + 7) & ~(size_t)7;
  const size_t oGhist     = off; off += (size_t)NBATCH * NHB * 4;
  off = (off + 7) & ~(size_t)7;
  const size_t oBucketKeys = off; off += NP * SPECCAP * 8;

  float* keptScore = (float*)(ws + oKeptScore);
  int* keptN = (int*)(ws + oKeptN);
  int* keptCount = (int*)(ws + oKeptCount);
  u32* bucketCnt = (u32*)(ws + oBucketCnt);
  u32* totCnt = (u32*)(ws + oTotCnt);
  u32* gtail = (u32*)(ws + oGtail);
  u32* ghist = (u32*)(ws + oGhist);
  u64* bucketKeys = (u64*)(ws + oBucketKeys);

  const int gBlocks = (NBOX + GBOX - 1) / GBOX;  // 157 per batch

  k_init<<<NBATCH, 256, 0, stream>>>(ghist, gtail, bucketCnt, totCnt);
  k_gather<<<dim3(gBlocks, NBATCH), 256, 0, stream>>>(cls, bucketKeys,
                                                      bucketCnt, totCnt);
  k_nms<<<NP, 512, 0, stream>>>(boxes, cls, bucketKeys, bucketCnt, totCnt,
                                keptScore, keptN, keptCount, ghist, gtail);
  k_osort<<<NBATCH, 256, 0, stream>>>(boxes, rel, keptScore, keptN, ghist, gtail, out);
}

// Round 17
// 128.405 us; speedup vs baseline: 4.1028x; 1.1101x over previous
//
#include <hip/hip_runtime.h>
#include <hip/hip_bf16.h>
#include <math.h>

#define NBATCH 8
#define NBOX   20000
#define NCLS   80
#define NREL   51
#define MAXDET 300
#define NTOT   (NCLS * MAXDET)      // 24000
#define CAP    512
#define SPECCAP 2560
#define NHB    3584                 // 512-ULP buckets over (0.9, 1.0]
#define HB0    (0x3F666666u >> 9)   // bucket base = bits(0.9f) >> 9
#define TARGETK 480u
#define SCORE_THR 0.05f
#define SPEC_THRF 0.9f
#define WWAVES 8
#define QPB    2560                 // float4 per gather block (= 128 boxes)
#define QTOT   (NBOX * NCLS / 4)    // 400000 float4 per batch
#define KCAP   40                   // staged keys per class per block (~8 sigma)

typedef unsigned long long u64;
typedef unsigned int u32;

// IoU > 0.5, explicit IEEE div (slow path only).
__device__ __forceinline__ bool iou_sup(float ax1, float ay1, float ax2, float ay2, float aarea,
                                        float bx1, float by1, float bx2, float by2, float barea) {
  float ix1 = fmaxf(ax1, bx1);
  float iy1 = fmaxf(ay1, by1);
  float ix2 = fminf(ax2, bx2);
  float iy2 = fminf(ay2, by2);
  float dw = fmaxf(__fsub_rn(ix2, ix1), 0.0f);
  float dh = fmaxf(__fsub_rn(iy2, iy1), 0.0f);
  float inter = __fmul_rn(dw, dh);
  float uni = __fsub_rn(__fadd_rn(aarea, barea), inter);
  if (!(uni > 0.0f)) return false;
  return __fdiv_rn(inter, uni) > 0.5f;
}

__device__ __forceinline__ bool iou_gt_half(float ax1, float ay1, float ax2, float ay2,
                                            float bx1, float by1, float bx2, float by2) {
  float aa = __fmul_rn(__fsub_rn(ax2, ax1), __fsub_rn(ay2, ay1));
  float ab = __fmul_rn(__fsub_rn(bx2, bx1), __fsub_rn(by2, by1));
  return iou_sup(ax1, ay1, ax2, ay2, aa, bx1, by1, bx2, by2, ab);
}

// Bit-exact div-free IoU>0.5 in PURE f32 (proof in round-9 notes).
__device__ __forceinline__ bool iou_sup_fast(float ax1, float ay1, float ax2, float ay2,
                                             float aarea, float bx1, float by1, float bx2,
                                             float by2, float barea) {
  float ix1 = fmaxf(ax1, bx1);
  float iy1 = fmaxf(ay1, by1);
  float ix2 = fminf(ax2, bx2);
  float iy2 = fminf(ay2, by2);
  float dw = fmaxf(__fsub_rn(ix2, ix1), 0.0f);
  float dh = fmaxf(__fsub_rn(iy2, iy1), 0.0f);
  float inter = __fmul_rn(dw, dh);
  float uni = __fsub_rn(__fadd_rn(aarea, barea), inter);
  return (uni > 0.0f) && (inter > __fmul_rn(0.5f, uni));
}

#define CEXR(x, y, asc) { bool sw_ = (asc) ? ((x) > (y)) : ((x) < (y)); \
                          if (sw_) { u64 t_ = (x); (x) = (y); (y) = t_; } }

// Bitonic sort ascending over SZ u64 keys in LDS.
template <int THREADS>
__device__ __forceinline__ void bitonic_sort(u64* keys, int SZ, int tid) {
  for (int k = 2; k <= SZ; k <<= 1) {
    for (int j = k >> 1; j >= 4; j >>= 1) {
      for (int v = tid; v < (SZ >> 1); v += THREADS) {
        int i = ((v & ~(j - 1)) << 1) | (v & (j - 1));
        int p = i | j;
        bool asc = ((i & k) == 0);
        u64 a = keys[i], b = keys[p];
        bool sw = asc ? (a > b) : (a < b);
        if (sw) { keys[i] = b; keys[p] = a; }
      }
      __syncthreads();
    }
    if (tid < (SZ >> 2)) {
      ulonglong2* k2 = (ulonglong2*)keys;
      ulonglong2 lo = k2[tid * 2], hi = k2[tid * 2 + 1];
      u64 a = lo.x, b = lo.y, c = hi.x, d = hi.y;
      int i0 = tid << 2;
      if (k == 2) {
        CEXR(a, b, true); CEXR(c, d, false);
      } else {
        bool asc = ((i0 & k) == 0);
        CEXR(a, c, asc); CEXR(b, d, asc);  // j = 2
        CEXR(a, b, asc); CEXR(c, d, asc);  // j = 1
      }
      lo.x = a; lo.y = b; hi.x = c; hi.y = d;
      k2[tid * 2] = lo; k2[tid * 2 + 1] = hi;
    }
    __syncthreads();
  }
}

// Barrier-light suffix select over NB buckets: minimal suffix >= min(total, cap).
// sout: [0]=bucket [1]=sel [2]=above [3]=total.
template <int NB, int THREADS>
__device__ __forceinline__ void suffix_fast(const u32* hist, u32 cap, u32* wsum, u32* sout) {
  const int tid = threadIdx.x, lane = tid & 63, w = tid >> 6;
  const int NW = THREADS / 64;
  const int G = NB / THREADS;
  u32 v = 0;
  const int hb = tid * G;
#pragma unroll
  for (int t = 0; t < G; ++t) v += hist[hb + t];
  u32 s = v;
#pragma unroll
  for (int off = 1; off < 64; off <<= 1) {
    u32 t2 = __shfl_down(s, off);
    if (lane + off < 64) s += t2;
  }
  if (lane == 0) wsum[w] = s;
  __syncthreads();
  u32 total = 0;
#pragma unroll
  for (int ww = 0; ww < NW; ++ww) total += wsum[ww];
  u32 after = 0;
#pragma unroll
  for (int ww = 1; ww < NW; ++ww) if (ww > w) after += wsum[ww];
  u32 inc = s + after;
  u32 exc = inc - v;
  if (tid == 0) {
    sout[3] = total;
    if (total == 0u) { sout[0] = 0u; sout[1] = 0u; sout[2] = 0u; }
  }
  u32 target = total < cap ? total : cap;
  if (total != 0u && inc >= target && exc < target) {  // exactly one thread
    u32 acc = exc;
    for (int u = hb + G - 1; u >= hb; --u) {
      acc += hist[u];
      if (acc >= target) { sout[0] = (u32)u; sout[1] = acc; sout[2] = acc - hist[u]; break; }
    }
  }
  __syncthreads();
}

// Zero all per-launch scratch.
__global__ __launch_bounds__(256) void k_init(u32* __restrict__ ghist,
                                              u32* __restrict__ gtail,
                                              u32* __restrict__ bucketCnt,
                                              u32* __restrict__ tailFlag) {
  const int b = blockIdx.x;
  const int tid = threadIdx.x;
  for (int i = tid; i < NHB; i += 256) ghist[b * NHB + i] = 0u;
  if (tid == 0) gtail[b] = 0u;
  for (int i = tid; i < NCLS; i += 256) {
    bucketCnt[b * NCLS + i] = 0u;
    tailFlag[b * NCLS + i] = 0u;
  }
}

// Pure streaming gather: coalesced float4 read of cls (native layout); spec (>0.9)
// elements route via LDS atomicAdd (mean 12.8/class/block) into per-class staging;
// tail (0.05,0.9] sets a per-class flag (broadcast read-check, ~80 writes/block).
// Flush: 80 parallel global atomics + contiguous copy. No transpose, no ballots.
// Bucket order nondeterministic; count-based select + full sort canonicalize.
__global__ __launch_bounds__(256) void k_gather(const float* __restrict__ cls,
                                                u64* __restrict__ bucketKeys,
                                                u32* __restrict__ bucketCnt,
                                                u32* __restrict__ tailFlag) {
  __shared__ u64 stKeys[NCLS][KCAP];         // 25600 B
  __shared__ u32 stCnt[NCLS], sBase[NCLS], stOvf[NCLS], tailL[NCLS];
  const int tid = threadIdx.x;
  const int lane = tid & 63;
  const int w = tid >> 6;
  const int b = blockIdx.y;
  const int q0 = blockIdx.x * QPB;
  const int qend = (q0 + QPB < QTOT) ? (q0 + QPB) : QTOT;
  const float4* src = (const float4*)(cls + (size_t)b * NBOX * NCLS);

  for (int i = tid; i < NCLS; i += 256) { stCnt[i] = 0u; stOvf[i] = 0u; tailL[i] = 0u; }
  __syncthreads();

  for (int base = q0; base < qend; base += 2048) {
    float4 v[8];
#pragma unroll
    for (int p = 0; p < 8; ++p) {
      int q = base + tid + (p << 8);
      if (q < qend) v[p] = src[q];
    }
#pragma unroll
    for (int p = 0; p < 8; ++p) {
      int q = base + tid + (p << 8);
      if (q < qend) {
        // C=80 divisible by 4 -> a float4 never crosses a box row.
        int nn = q / (NCLS / 4);
        int cb = (q - nn * (NCLS / 4)) * 4;
        float vv[4] = {v[p].x, v[p].y, v[p].z, v[p].w};
#pragma unroll
        for (int e = 0; e < 4; ++e) {
          float s = vv[e];
          int c = cb + e;
          if (s > SPEC_THRF) {
            u32 pos = atomicAdd(&stCnt[c], 1u);
            if (pos < KCAP)
              stKeys[c][pos] = ((u64)__float_as_uint(s) << 32) | (~(u32)nn);
            else
              stOvf[c] = 1u;            // benign same-value race
          } else if (s > SCORE_THR) {
            if (tailL[c] == 0u) tailL[c] = 1u;  // broadcast read, rare write
          }
        }
      }
    }
  }
  __syncthreads();

  // ONE atomic per class, 80 issued in parallel (latency overlapped).
  if (tid < NCLS) {
    if (tailL[tid]) tailFlag[b * NCLS + tid] = 1u;   // benign same-value race
    u32 cnt = stCnt[tid];
    u32 wr = cnt < KCAP ? cnt : (u32)KCAP;
    u32 add = wr + (stOvf[tid] ? (u32)(SPECCAP + 1) : 0u);
    u32 base = 0;
    if (add) base = atomicAdd(&bucketCnt[b * NCLS + tid], add);
    sBase[tid] = base;
    stCnt[tid] = wr;
  }
  __syncthreads();

  // Contiguous copy staged -> global buckets.
  for (int c = w; c < NCLS; c += 4) {
    u32 cnt = stCnt[c];
    u32 base = sBase[c];
    u64* dst = bucketKeys + (size_t)(b * NCLS + c) * SPECCAP;
    for (u32 i = lane; i < cnt; i += 64) {
      u32 pos = base + i;
      if (pos < SPECCAP) dst[pos] = stKeys[c][i];
    }
  }
}

// Exact reference-style greedy NMS (slow path), 512-thread, inline from k_nms.
__device__ void slow_path(const float* __restrict__ boxes,
                          const float* __restrict__ cls, int bc,
                          float* __restrict__ keptScore, int* __restrict__ keptN,
                          int* __restrict__ keptCount,
                          u32* __restrict__ ghist, u32* __restrict__ gtail,
                          char* smem) {
  u32* sup = (u32*)smem;                       // [(NBOX+31)/32] u32 @0
  u64* red = (u64*)(smem + 2560);              // [512] u64 @2560
  float4* sbx = (float4*)(smem + 6656);
  int* s_kept = (int*)(smem + 6672);
  const int tid = threadIdx.x;
  const int b = bc / NCLS, c = bc % NCLS;
  const float* col = cls + (size_t)b * NBOX * NCLS + c;

  for (int i = tid; i < (NBOX + 31) / 32; i += 512) sup[i] = 0u;
  if (tid == 0) *s_kept = 0;
  __syncthreads();
  for (int it = 0; it < MAXDET; ++it) {
    u64 best = 0ull;
    for (int n = tid; n < NBOX; n += 512) {
      if ((sup[n >> 5] >> (n & 31)) & 1u) continue;
      float s = col[(size_t)n * NCLS];
      if (s > SCORE_THR) {
        u64 key = ((u64)__float_as_uint(s) << 32) | (~(u32)n);
        if (key > best) best = key;
      }
    }
    red[tid] = best;
    __syncthreads();
    for (int off = 256; off > 0; off >>= 1) {
      if (tid < off) { u64 o = red[tid + off]; if (o > red[tid]) red[tid] = o; }
      __syncthreads();
    }
    u64 win = red[0];
    if (win == 0ull) break;
    u32 nw = ~((u32)win);
    if (tid == 0) {
      int k = *s_kept;
      keptScore[bc * MAXDET + k] = __uint_as_float((u32)(win >> 32));
      keptN[bc * MAXDET + k] = (int)nw;
      *s_kept = k + 1;
      *sbx = ((const float4*)boxes)[(size_t)b * NBOX + nw];
    }
    __syncthreads();
    float4 bx = *sbx;
    for (int n = tid; n < NBOX; n += 512) {
      float4 cb = ((const float4*)boxes)[(size_t)b * NBOX + n];
      if (iou_gt_half(bx.x, bx.y, bx.z, bx.w, cb.x, cb.y, cb.z, cb.w))
        atomicOr(&sup[n >> 5], 1u << (n & 31));
    }
    if (tid == 0) atomicOr(&sup[nw >> 5], 1u << (nw & 31));
    __syncthreads();
  }
  __syncthreads();
  const int kept = *s_kept;
  for (int r = kept + tid; r < MAXDET; r += 512) {
    keptScore[bc * MAXDET + r] = -INFINITY;
    keptN[bc * MAXDET + r] = 0;
  }
  for (int rr = tid; rr < kept; rr += 512) {
    float s = keptScore[bc * MAXDET + rr];
    if (s > SPEC_THRF) {
      u32 h = (__float_as_uint(s) >> 9) - HB0;
      if (h > NHB - 1) h = NHB - 1;
      atomicAdd(&ghist[b * NHB + h], 1u);
    } else {
      atomicAdd(&gtail[b], 1u);
    }
  }
  if (tid == 0) keptCount[bc] = kept;
}

// Fused per-(b,c) kernel: bucket load -> LDS histogram select -> compact ->
// bitonic-512 -> round-13 tile-parallel greedy walk (frozen). Slow path inline.
// Tail flag replaces exact totals: if no tail, total == specCount (exact); if
// tail && spec >= TARGETK, target = TARGETK (exact); else slow path.
__global__ __launch_bounds__(512) void k_nms(const float* __restrict__ boxes,
                                             const float* __restrict__ cls,
                                             const u64* __restrict__ bucketKeys,
                                             const u32* __restrict__ bucketCnt,
                                             const u32* __restrict__ tailFlag,
                                             float* __restrict__ keptScore,
                                             int* __restrict__ keptN,
                                             int* __restrict__ keptCount,
                                             u32* __restrict__ ghist,
                                             u32* __restrict__ gtail) {
  __shared__ __align__(16) char smem[38912];
  u64* side = (u64*)smem;
  u32* hist = (u32*)(smem + 20480);
  u64* keys = (u64*)(smem + 34816);
  float4* candbox = (float4*)smem;
  float* carea = (float*)(smem + 8192);
  float4* keptbox = (float4*)(smem + 10240);
  float* karea = (float*)(smem + 15040);
  int* kn = (int*)(smem + 16240);
  float* ksc = (float*)(smem + 17440);
  __shared__ u32 wsum[WWAVES], selB[4];
  __shared__ u32 s_cnt;
  __shared__ u64 supW[WWAVES];
  __shared__ u64 mpart[WWAVES][64];
  __shared__ int s_kept;

  const int tid = threadIdx.x;
  const int lane = tid & 63;
  const int w = tid >> 6;
  const u64 lmask = (1ull << lane) - 1ull;
  const int bc = blockIdx.x;
  const int b = bc / NCLS;

  const u32 specRaw = bucketCnt[bc];
  const u32 tailF = tailFlag[bc];

  if (specRaw == 0u && tailF == 0u) {  // no candidates at all
    for (int r = tid; r < MAXDET; r += 512) {
      keptScore[bc * MAXDET + r] = -INFINITY;
      keptN[bc * MAXDET + r] = 0;
    }
    if (tid == 0) keptCount[bc] = 0;
    return;
  }
  // Slow path if: bucket overflow, or tail present with too few spec keys.
  if (specRaw > SPECCAP || (tailF != 0u && specRaw < TARGETK)) {
    slow_path(boxes, cls, bc, keptScore, keptN, keptCount, ghist, gtail, smem);
    return;
  }
  const u32 specCount = specRaw;
  const u32 target = (tailF == 0u)
                         ? (specCount < TARGETK ? specCount : TARGETK)
                         : TARGETK;

  const u64* bk = bucketKeys + (size_t)bc * SPECCAP;
  for (int i = tid; i < (int)specCount; i += 512) side[i] = bk[i];
  for (int i = tid; i < NHB; i += 512) hist[i] = 0u;
  if (tid == 0) { s_cnt = 0u; s_kept = 0; }
  __syncthreads();
  for (int i = tid; i < (int)specCount; i += 512) {
    u32 bits = (u32)(side[i] >> 32);
    u32 h = (bits >> 9) - HB0;
    if (h > NHB - 1) h = NHB - 1;
    atomicAdd(&hist[h], 1u);
  }
  __syncthreads();

  suffix_fast<NHB, 512>(hist, target, wsum, selB);
  const u32 F0 = selB[0];
  const u32 selCount = selB[1];
  if (selCount > CAP) {
    __syncthreads();
    slow_path(boxes, cls, bc, keptScore, keptN, keptCount, ghist, gtail, smem);
    return;
  }

  const int iters = (int)((specCount + 511u) >> 9);
  for (int it2 = 0; it2 < iters; ++it2) {
    u32 idx = (u32)it2 * 512u + (u32)tid;
    bool act = idx < specCount;
    u64 key = act ? side[idx] : 0ull;
    u32 bits = (u32)(key >> 32);
    u32 h = (bits >> 9) - HB0;
    if (h > NHB - 1) h = NHB - 1;
    bool sel = act && (h >= F0);
    u64 ms = __ballot(sel);
    if (ms) {
      u32 bs;
      if (lane == 0) bs = atomicAdd(&s_cnt, (u32)__popcll(ms));
      bs = __shfl(bs, 0);
      if (sel) keys[bs + (u32)__popcll(ms & lmask)] = key;
    }
  }
  __syncthreads();
  for (int i = (int)selCount + tid; i < CAP; i += 512) keys[i] = 0ull;
  __syncthreads();

  bitonic_sort<512>(keys, CAP, tid);

  for (int i = tid; i < (int)selCount; i += 512) {
    int pos = CAP - 1 - i;
    u32 n = ~((u32)keys[pos]);
    float4 bb = ((const float4*)boxes)[(size_t)b * NBOX + n];
    candbox[pos] = bb;
    carea[pos] = __fmul_rn(__fsub_rn(bb.z, bb.x), __fsub_rn(bb.w, bb.y));
  }
  __syncthreads();

  const u32 ntile = (selCount + 63u) >> 6;
  for (u32 t = 0; t < ntile; ++t) {
    const int kept0 = s_kept;
    if (kept0 >= MAXDET) break;
    const u32 r = t * 64u + (u32)lane;
    const bool valid = r < selCount;
    const int si = valid ? (CAP - 1 - (int)r) : (CAP - 1);
    float4 mybox = candbox[si];
    float marea = carea[si];
    bool sup = false;
    for (int k = w; k < kept0; k += WWAVES) {
      float4 kb = keptbox[k];
      if (iou_sup_fast(kb.x, kb.y, kb.z, kb.w, karea[k],
                       mybox.x, mybox.y, mybox.z, mybox.w, marea))
        sup = true;
    }
    u64 bal = __ballot(sup);
    if (lane == 0) supW[w] = bal;
    u64 mw = 0ull;
    const int ebase = w * 8;
#pragma unroll
    for (int ee = 0; ee < 8; ++ee) {
      const int e = ebase + ee;
      int ei = CAP - 1 - (int)(t * 64u) - e;
      float4 eb = candbox[ei];
      if (e < lane && iou_sup_fast(eb.x, eb.y, eb.z, eb.w, carea[ei],
                                   mybox.x, mybox.y, mybox.z, mybox.w, marea))
        mw |= 1ull << e;
    }
    mpart[w][lane] = mw;
    __syncthreads();
    if (w == 0) {
      u64 prior = 0ull, m = 0ull;
#pragma unroll
      for (int ww = 0; ww < WWAVES; ++ww) {
        prior |= supW[ww];
        m |= mpart[ww][lane];
      }
      u64 remaining = __ballot(valid) & ~prior;
      u64 keptmask = 0ull;
      const int room = MAXDET - kept0;
      while (remaining != 0ull && (int)__popcll(keptmask) < room) {
        int j = __ffsll((long long)remaining) - 1;
        keptmask |= 1ull << j;
        remaining &= ~(1ull << j);
        u64 supj = __ballot(((m >> j) & 1ull) != 0ull);
        remaining &= ~supj;
      }
      if ((keptmask >> lane) & 1ull) {
        int pos = kept0 + (int)__popcll(keptmask & lmask);
        u64 mykey = keys[CAP - 1 - (int)r];
        keptbox[pos] = mybox;
        karea[pos] = marea;
        kn[pos] = (int)(~((u32)mykey));
        ksc[pos] = __uint_as_float((u32)(mykey >> 32));
      }
      if (lane == 0) s_kept = kept0 + (int)__popcll(keptmask);
    }
    __syncthreads();
  }

  const int kept = s_kept;
  const bool exhausted = (kept < MAXDET) && (selCount < specCount || tailF != 0u);
  if (exhausted) {
    __syncthreads();
    slow_path(boxes, cls, bc, keptScore, keptN, keptCount, ghist, gtail, smem);
    return;
  }
  for (int rr = tid; rr < MAXDET; rr += 512) {
    keptScore[bc * MAXDET + rr] = (rr < kept) ? ksc[rr] : -INFINITY;
    keptN[bc * MAXDET + rr] = (rr < kept) ? kn[rr] : 0;
  }
  if (tid == 0) keptCount[bc] = kept;
  for (int rr = tid; rr < kept; rr += 512) {
    float s = ksc[rr];
    if (s > SPEC_THRF) {
      u32 h = (__float_as_uint(s) >> 9) - HB0;
      if (h > NHB - 1) h = NHB - 1;
      atomicAdd(&ghist[b * NHB + h], 1u);
    } else {
      atomicAdd(&gtail[b], 1u);
    }
  }
}

// Top-k + outputs (unchanged).
__global__ __launch_bounds__(256) void k_osort(const float* __restrict__ boxes,
                                               const float* __restrict__ rel,
                                               const float* __restrict__ keptScore,
                                               const int* __restrict__ keptN,
                                               const u32* __restrict__ ghist,
                                               const u32* __restrict__ gtail,
                                               float* __restrict__ out) {
  __shared__ u64 keys[1024];
  __shared__ u32 wsum[4], selB[4];
  __shared__ u32 s_cnt;
  const int tid = threadIdx.x;
  const int lane = tid & 63;
  const u64 lmask = (1ull << lane) - 1ull;
  const int b = blockIdx.x;
  const float4* ks4 = (const float4*)(keptScore + (size_t)b * NTOT);

  if (tid == 0) s_cnt = 0u;
  suffix_fast<NHB, 256>(ghist + (size_t)b * NHB, (u32)MAXDET, wsum, selB);
  const u32 specTotal = selB[3];
  const u32 totalAll = specTotal + gtail[b];
  const u32 target = totalAll < (u32)MAXDET ? totalAll : (u32)MAXDET;
  const u32 F0 = selB[0];
  const u32 selSpec = selB[1];
  const bool fast = (totalAll != 0u) && (specTotal >= target) && (selSpec <= (u32)CAP);
  int SZ = CAP;

  if (totalAll != 0u) {
    if (fast) {
      for (int base = 0; base < NTOT / 4; base += 2048) {
        float4 v[8];
#pragma unroll
        for (int p = 0; p < 8; ++p) {
          int q = base + tid + (p << 8);
          if (q < NTOT / 4) v[p] = ks4[q];
        }
#pragma unroll
        for (int p = 0; p < 8; ++p) {
          int q = base + tid + (p << 8);
          if (q < NTOT / 4) {
            float vv[4] = {v[p].x, v[p].y, v[p].z, v[p].w};
#pragma unroll
            for (int e = 0; e < 4; ++e) {
              float s = vv[e];
              bool sel = false;
              u32 bits = 0;
              if (s > SPEC_THRF) {
                bits = __float_as_uint(s);
                u32 h = (bits >> 9) - HB0;
                if (h > NHB - 1) h = NHB - 1;
                sel = (h >= F0);
              }
              u64 ms = __ballot(sel);
              if (ms) {
                u32 bs;
                if (lane == 0) bs = atomicAdd(&s_cnt, (u32)__popcll(ms));
                bs = __shfl(bs, 0);
                if (sel)
                  keys[bs + (u32)__popcll(ms & lmask)] =
                      ((u64)bits << 32) | (~(u32)(q * 4 + e));
              }
            }
          }
        }
      }
      __syncthreads();
      for (int i = (int)selSpec + tid; i < CAP; i += 256) keys[i] = 0ull;
      __syncthreads();
      bitonic_sort<256>(keys, CAP, tid);
      SZ = CAP;
    } else {
      if (tid < 64) {
        const int c0 = lane, c1 = 64 + lane;
        const bool has1 = (c1 < NCLS);
        const float* ls0 = keptScore + ((size_t)b * NCLS + c0) * MAXDET;
        const float* ls1 = keptScore + ((size_t)b * NCLS + (has1 ? c1 : c0)) * MAXDET;
        int h0 = 0, h1 = 0;
        float v0 = ls0[0], w0v = ls0[1];
        float v1 = has1 ? ls1[0] : -INFINITY;
        float w1v = has1 ? ls1[1] : -INFINITY;
        for (int r = 0; r < (int)target; ++r) {
          float bs; int bcl;
          if (has1 && v1 > v0) { bs = v1; bcl = c1; } else { bs = v0; bcl = c0; }
#pragma unroll
          for (int off = 32; off > 0; off >>= 1) {
            float os = __shfl_xor(bs, off);
            int oc = __shfl_xor(bcl, off);
            if (os > bs || (os == bs && oc < bcl)) { bs = os; bcl = oc; }
          }
          if (bcl == c0) {
            keys[1023 - r] = ((u64)__float_as_uint(bs) << 32) | (~(u32)(c0 * MAXDET + h0));
            ++h0; v0 = w0v; w0v = (h0 + 1 < MAXDET) ? ls0[h0 + 1] : -INFINITY;
          } else if (has1 && bcl == c1) {
            keys[1023 - r] = ((u64)__float_as_uint(bs) << 32) | (~(u32)(c1 * MAXDET + h1));
            ++h1; v1 = w1v; w1v = (h1 + 1 < MAXDET) ? ls1[h1 + 1] : -INFINITY;
          }
        }
      }
      __syncthreads();
      SZ = 1024;
    }
  }

  for (int r = tid; r < MAXDET; r += 256) {
    const bool valid = (u32)r < target;
    float s = -1.0f, pm = -1.0f, pl = -1.0f, cl = -1.0f;
    float4 ob; ob.x = ob.y = ob.z = ob.w = -1.0f;
    if (valid) {
      u64 key = keys[SZ - 1 - r];
      u32 fp = ~((u32)key);
      int c = (int)(fp / MAXDET);
      int slot = (int)(fp - (u32)c * MAXDET);
      int n = keptN[((size_t)b * NCLS + c) * MAXDET + slot];
      s = __uint_as_float((u32)(key >> 32));
      cl = (float)c;
      size_t nb = (size_t)b * NBOX + (u32)n;
      ob = ((const float4*)boxes)[nb];
      const float* rp = rel + nb * NREL;
      float vr[NREL];
#pragma unroll
      for (int p = 0; p < NREL; ++p) vr[p] = rp[p];
      float best = vr[0]; int bi = 0;
#pragma unroll
      for (int p = 1; p < NREL; ++p) { if (vr[p] > best) { best = vr[p]; bi = p; } }
      pm = best; pl = (float)bi;
    }
    ((float4*)out)[(size_t)b * MAXDET + r] = ob;
    const int sbase = NBATCH * MAXDET * 4;
    out[sbase + b * MAXDET + r] = s;
    out[sbase + NBATCH * MAXDET + b * MAXDET + r] = cl;
    out[sbase + 2 * NBATCH * MAXDET + b * MAXDET + r] = pm;
    out[sbase + 3 * NBATCH * MAXDET + b * MAXDET + r] = pl;
  }
}

extern "C" void kernel_launch(void* const* d_in, const int* in_sizes, int n_in,
                              void* d_out, int out_size, void* d_ws, size_t ws_size,
                              hipStream_t stream) {
  (void)in_sizes; (void)n_in; (void)out_size; (void)ws_size;
  const float* boxes = (const float*)d_in[0];
  const float* cls   = (const float*)d_in[1];
  const float* rel   = (const float*)d_in[2];
  float* out = (float*)d_out;
  char* ws = (char*)d_ws;

  const size_t NP = NBATCH * NCLS;  // 640 problems
  size_t off = 0;
  const size_t oKeptScore = off; off += NP * MAXDET * 4;
  const size_t oKeptN     = off; off += NP * MAXDET * 4;
  const size_t oKeptCount = off; off += NP * 4;
  const size_t oBucketCnt = off; off += NP * 4;
  const size_t oTailFlag  = off; off += NP * 4;
  const size_t oGtail     = off; off += NBATCH * 4;
  off = (off + 7) & ~(size_t)7;
  const size_t oGhist     = off; off += (size_t)NBATCH * NHB * 4;
  off = (off + 7) & ~(size_t)7;
  const size_t oBucketKeys = off; off += NP * SPECCAP * 8;

  float* keptScore = (float*)(ws + oKeptScore);
  int* keptN = (int*)(ws + oKeptN);
  int* keptCount = (int*)(ws + oKeptCount);
  u32* bucketCnt = (u32*)(ws + oBucketCnt);
  u32* tailFlag = (u32*)(ws + oTailFlag);
  u32* gtail = (u32*)(ws + oGtail);
  u32* ghist = (u32*)(ws + oGhist);
  u64* bucketKeys = (u64*)(ws + oBucketKeys);

  const int gBlocks = (QTOT + QPB - 1) / QPB;  // 157 per batch

  k_init<<<NBATCH, 256, 0, stream>>>(ghist, gtail, bucketCnt, tailFlag);
  k_gather<<<dim3(gBlocks, NBATCH), 256, 0, stream>>>(cls, bucketKeys,
                                                      bucketCnt, tailFlag);
  k_nms<<<NP, 512, 0, stream>>>(boxes, cls, bucketKeys, bucketCnt, tailFlag,
                                keptScore, keptN, keptCount, ghist, gtail);
  k_osort<<<NBATCH, 256, 0, stream>>>(boxes, rel, keptScore, keptN, ghist, gtail, out);
}

// Round 18
// 128.312 us; speedup vs baseline: 4.1058x; 1.0007x over previous
//
#include <hip/hip_runtime.h>
#include <hip/hip_bf16.h>
#include <math.h>

#define NBATCH 8
#define NBOX   20000
#define NCLS   80
#define NREL   51
#define MAXDET 300
#define NTOT   (NCLS * MAXDET)      // 24000
#define CAP    512
#define SPECCAP 2560
#define NHB    3584                 // 512-ULP buckets over (0.9, 1.0]
#define HB0    (0x3F666666u >> 9)   // bucket base = bits(0.9f) >> 9
#define TARGETK 480u
#define SCORE_THR 0.05f
#define SPEC_THRF 0.9f
#define WWAVES 8
#define QPB    2560                 // float4 per gather block (= 128 boxes)
#define QTOT   (NBOX * NCLS / 4)    // 400000 float4 per batch
#define KCAP   40                   // staged keys per class per block (~8 sigma)

typedef unsigned long long u64;
typedef unsigned int u32;

// IoU > 0.5, explicit IEEE div (slow path only).
__device__ __forceinline__ bool iou_sup(float ax1, float ay1, float ax2, float ay2, float aarea,
                                        float bx1, float by1, float bx2, float by2, float barea) {
  float ix1 = fmaxf(ax1, bx1);
  float iy1 = fmaxf(ay1, by1);
  float ix2 = fminf(ax2, bx2);
  float iy2 = fminf(ay2, by2);
  float dw = fmaxf(__fsub_rn(ix2, ix1), 0.0f);
  float dh = fmaxf(__fsub_rn(iy2, iy1), 0.0f);
  float inter = __fmul_rn(dw, dh);
  float uni = __fsub_rn(__fadd_rn(aarea, barea), inter);
  if (!(uni > 0.0f)) return false;
  return __fdiv_rn(inter, uni) > 0.5f;
}

__device__ __forceinline__ bool iou_gt_half(float ax1, float ay1, float ax2, float ay2,
                                            float bx1, float by1, float bx2, float by2) {
  float aa = __fmul_rn(__fsub_rn(ax2, ax1), __fsub_rn(ay2, ay1));
  float ab = __fmul_rn(__fsub_rn(bx2, bx1), __fsub_rn(by2, by1));
  return iou_sup(ax1, ay1, ax2, ay2, aa, bx1, by1, bx2, by2, ab);
}

// Bit-exact div-free IoU>0.5 in PURE f32 (proof in round-9 notes).
__device__ __forceinline__ bool iou_sup_fast(float ax1, float ay1, float ax2, float ay2,
                                             float aarea, float bx1, float by1, float bx2,
                                             float by2, float barea) {
  float ix1 = fmaxf(ax1, bx1);
  float iy1 = fmaxf(ay1, by1);
  float ix2 = fminf(ax2, bx2);
  float iy2 = fminf(ay2, by2);
  float dw = fmaxf(__fsub_rn(ix2, ix1), 0.0f);
  float dh = fmaxf(__fsub_rn(iy2, iy1), 0.0f);
  float inter = __fmul_rn(dw, dh);
  float uni = __fsub_rn(__fadd_rn(aarea, barea), inter);
  return (uni > 0.0f) && (inter > __fmul_rn(0.5f, uni));
}

#define CEXR(x, y, asc) { bool sw_ = (asc) ? ((x) > (y)) : ((x) < (y)); \
                          if (sw_) { u64 t_ = (x); (x) = (y); (y) = t_; } }

// Bitonic sort ascending over SZ u64 keys in LDS.
template <int THREADS>
__device__ __forceinline__ void bitonic_sort(u64* keys, int SZ, int tid) {
  for (int k = 2; k <= SZ; k <<= 1) {
    for (int j = k >> 1; j >= 4; j >>= 1) {
      for (int v = tid; v < (SZ >> 1); v += THREADS) {
        int i = ((v & ~(j - 1)) << 1) | (v & (j - 1));
        int p = i | j;
        bool asc = ((i & k) == 0);
        u64 a = keys[i], b = keys[p];
        bool sw = asc ? (a > b) : (a < b);
        if (sw) { keys[i] = b; keys[p] = a; }
      }
      __syncthreads();
    }
    if (tid < (SZ >> 2)) {
      ulonglong2* k2 = (ulonglong2*)keys;
      ulonglong2 lo = k2[tid * 2], hi = k2[tid * 2 + 1];
      u64 a = lo.x, b = lo.y, c = hi.x, d = hi.y;
      int i0 = tid << 2;
      if (k == 2) {
        CEXR(a, b, true); CEXR(c, d, false);
      } else {
        bool asc = ((i0 & k) == 0);
        CEXR(a, c, asc); CEXR(b, d, asc);  // j = 2
        CEXR(a, b, asc); CEXR(c, d, asc);  // j = 1
      }
      lo.x = a; lo.y = b; hi.x = c; hi.y = d;
      k2[tid * 2] = lo; k2[tid * 2 + 1] = hi;
    }
    __syncthreads();
  }
}

// Barrier-light suffix select over NB buckets: minimal suffix >= min(total, cap).
// sout: [0]=bucket [1]=sel [2]=above [3]=total.
template <int NB, int THREADS>
__device__ __forceinline__ void suffix_fast(const u32* hist, u32 cap, u32* wsum, u32* sout) {
  const int tid = threadIdx.x, lane = tid & 63, w = tid >> 6;
  const int NW = THREADS / 64;
  const int G = NB / THREADS;
  u32 v = 0;
  const int hb = tid * G;
#pragma unroll
  for (int t = 0; t < G; ++t) v += hist[hb + t];
  u32 s = v;
#pragma unroll
  for (int off = 1; off < 64; off <<= 1) {
    u32 t2 = __shfl_down(s, off);
    if (lane + off < 64) s += t2;
  }
  if (lane == 0) wsum[w] = s;
  __syncthreads();
  u32 total = 0;
#pragma unroll
  for (int ww = 0; ww < NW; ++ww) total += wsum[ww];
  u32 after = 0;
#pragma unroll
  for (int ww = 1; ww < NW; ++ww) if (ww > w) after += wsum[ww];
  u32 inc = s + after;
  u32 exc = inc - v;
  if (tid == 0) {
    sout[3] = total;
    if (total == 0u) { sout[0] = 0u; sout[1] = 0u; sout[2] = 0u; }
  }
  u32 target = total < cap ? total : cap;
  if (total != 0u && inc >= target && exc < target) {  // exactly one thread
    u32 acc = exc;
    for (int u = hb + G - 1; u >= hb; --u) {
      acc += hist[u];
      if (acc >= target) { sout[0] = (u32)u; sout[1] = acc; sout[2] = acc - hist[u]; break; }
    }
  }
  __syncthreads();
}

// Zero all per-launch scratch.
__global__ __launch_bounds__(256) void k_init(u32* __restrict__ ghist,
                                              u32* __restrict__ gtail,
                                              u32* __restrict__ bucketCnt,
                                              u32* __restrict__ tailFlag) {
  const int b = blockIdx.x;
  const int tid = threadIdx.x;
  for (int i = tid; i < NHB; i += 256) ghist[b * NHB + i] = 0u;
  if (tid == 0) gtail[b] = 0u;
  for (int i = tid; i < NCLS; i += 256) {
    bucketCnt[b * NCLS + i] = 0u;
    tailFlag[b * NCLS + i] = 0u;
  }
}

// Pure streaming gather (round-17, frozen): coalesced float4 read; spec (>0.9) ->
// LDS atomicAdd staging; tail -> per-class flag; flush = 80 parallel global atomics
// + contiguous copy. Bucket order nondeterministic; downstream sort canonicalizes.
__global__ __launch_bounds__(256) void k_gather(const float* __restrict__ cls,
                                                u64* __restrict__ bucketKeys,
                                                u32* __restrict__ bucketCnt,
                                                u32* __restrict__ tailFlag) {
  __shared__ u64 stKeys[NCLS][KCAP];         // 25600 B
  __shared__ u32 stCnt[NCLS], sBase[NCLS], stOvf[NCLS], tailL[NCLS];
  const int tid = threadIdx.x;
  const int lane = tid & 63;
  const int w = tid >> 6;
  const int b = blockIdx.y;
  const int q0 = blockIdx.x * QPB;
  const int qend = (q0 + QPB < QTOT) ? (q0 + QPB) : QTOT;
  const float4* src = (const float4*)(cls + (size_t)b * NBOX * NCLS);

  for (int i = tid; i < NCLS; i += 256) { stCnt[i] = 0u; stOvf[i] = 0u; tailL[i] = 0u; }
  __syncthreads();

  for (int base = q0; base < qend; base += 2048) {
    float4 v[8];
#pragma unroll
    for (int p = 0; p < 8; ++p) {
      int q = base + tid + (p << 8);
      if (q < qend) v[p] = src[q];
    }
#pragma unroll
    for (int p = 0; p < 8; ++p) {
      int q = base + tid + (p << 8);
      if (q < qend) {
        int nn = q / (NCLS / 4);
        int cb = (q - nn * (NCLS / 4)) * 4;
        float vv[4] = {v[p].x, v[p].y, v[p].z, v[p].w};
#pragma unroll
        for (int e = 0; e < 4; ++e) {
          float s = vv[e];
          int c = cb + e;
          if (s > SPEC_THRF) {
            u32 pos = atomicAdd(&stCnt[c], 1u);
            if (pos < KCAP)
              stKeys[c][pos] = ((u64)__float_as_uint(s) << 32) | (~(u32)nn);
            else
              stOvf[c] = 1u;            // benign same-value race
          } else if (s > SCORE_THR) {
            if (tailL[c] == 0u) tailL[c] = 1u;  // broadcast read, rare write
          }
        }
      }
    }
  }
  __syncthreads();

  if (tid < NCLS) {
    if (tailL[tid]) tailFlag[b * NCLS + tid] = 1u;   // benign same-value race
    u32 cnt = stCnt[tid];
    u32 wr = cnt < KCAP ? cnt : (u32)KCAP;
    u32 add = wr + (stOvf[tid] ? (u32)(SPECCAP + 1) : 0u);
    u32 base = 0;
    if (add) base = atomicAdd(&bucketCnt[b * NCLS + tid], add);
    sBase[tid] = base;
    stCnt[tid] = wr;
  }
  __syncthreads();

  for (int c = w; c < NCLS; c += 4) {
    u32 cnt = stCnt[c];
    u32 base = sBase[c];
    u64* dst = bucketKeys + (size_t)(b * NCLS + c) * SPECCAP;
    for (u32 i = lane; i < cnt; i += 64) {
      u32 pos = base + i;
      if (pos < SPECCAP) dst[pos] = stKeys[c][i];
    }
  }
}

// Exact reference-style greedy NMS (slow path), 512-thread, inline from k_nms.
__device__ void slow_path(const float* __restrict__ boxes,
                          const float* __restrict__ cls, int bc,
                          float* __restrict__ keptScore, int* __restrict__ keptN,
                          int* __restrict__ keptCount,
                          u32* __restrict__ ghist, u32* __restrict__ gtail,
                          char* smem) {
  u32* sup = (u32*)smem;                       // [(NBOX+31)/32] u32 @0
  u64* red = (u64*)(smem + 2560);              // [512] u64 @2560
  float4* sbx = (float4*)(smem + 6656);
  int* s_kept = (int*)(smem + 6672);
  const int tid = threadIdx.x;
  const int b = bc / NCLS, c = bc % NCLS;
  const float* col = cls + (size_t)b * NBOX * NCLS + c;

  for (int i = tid; i < (NBOX + 31) / 32; i += 512) sup[i] = 0u;
  if (tid == 0) *s_kept = 0;
  __syncthreads();
  for (int it = 0; it < MAXDET; ++it) {
    u64 best = 0ull;
    for (int n = tid; n < NBOX; n += 512) {
      if ((sup[n >> 5] >> (n & 31)) & 1u) continue;
      float s = col[(size_t)n * NCLS];
      if (s > SCORE_THR) {
        u64 key = ((u64)__float_as_uint(s) << 32) | (~(u32)n);
        if (key > best) best = key;
      }
    }
    red[tid] = best;
    __syncthreads();
    for (int off = 256; off > 0; off >>= 1) {
      if (tid < off) { u64 o = red[tid + off]; if (o > red[tid]) red[tid] = o; }
      __syncthreads();
    }
    u64 win = red[0];
    if (win == 0ull) break;
    u32 nw = ~((u32)win);
    if (tid == 0) {
      int k = *s_kept;
      keptScore[bc * MAXDET + k] = __uint_as_float((u32)(win >> 32));
      keptN[bc * MAXDET + k] = (int)nw;
      *s_kept = k + 1;
      *sbx = ((const float4*)boxes)[(size_t)b * NBOX + nw];
    }
    __syncthreads();
    float4 bx = *sbx;
    for (int n = tid; n < NBOX; n += 512) {
      float4 cb = ((const float4*)boxes)[(size_t)b * NBOX + n];
      if (iou_gt_half(bx.x, bx.y, bx.z, bx.w, cb.x, cb.y, cb.z, cb.w))
        atomicOr(&sup[n >> 5], 1u << (n & 31));
    }
    if (tid == 0) atomicOr(&sup[nw >> 5], 1u << (nw & 31));
    __syncthreads();
  }
  __syncthreads();
  const int kept = *s_kept;
  for (int r = kept + tid; r < MAXDET; r += 512) {
    keptScore[bc * MAXDET + r] = -INFINITY;
    keptN[bc * MAXDET + r] = 0;
  }
  for (int rr = tid; rr < kept; rr += 512) {
    float s = keptScore[bc * MAXDET + rr];
    if (s > SPEC_THRF) {
      u32 h = (__float_as_uint(s) >> 9) - HB0;
      if (h > NHB - 1) h = NHB - 1;
      atomicAdd(&ghist[b * NHB + h], 1u);
    } else {
      atomicAdd(&gtail[b], 1u);
    }
  }
  if (tid == 0) keptCount[bc] = kept;
}

// Fused per-(b,c) kernel, LDS-slim: hist + compact read the (L2-resident) bucket
// DIRECTLY from global (no side staging) -> bitonic-512 -> frozen round-13 walk.
// LDS 38.9 -> 22.8 KB => 4 blocks/CU (wave-capped) for better overlap.
__global__ __launch_bounds__(512) void k_nms(const float* __restrict__ boxes,
                                             const float* __restrict__ cls,
                                             const u64* __restrict__ bucketKeys,
                                             const u32* __restrict__ bucketCnt,
                                             const u32* __restrict__ tailFlag,
                                             float* __restrict__ keptScore,
                                             int* __restrict__ keptN,
                                             int* __restrict__ keptCount,
                                             u32* __restrict__ ghist,
                                             u32* __restrict__ gtail) {
  // keys u64[512]@0 (4096). Select: hist u32[3584]@4096 (ends 18432).
  // Walk aliasing (hist dead): candbox f4[512]@4096 (->12288); carea@12288
  // (->14336); keptbox f4[300]@14336 (->19136); karea@19136; kn@20336; ksc@21536
  // (ends 22736). Slow aliasing @0: sup 2560; red@2560; sbx@6656; s_kept@6672.
  __shared__ __align__(16) char smem[22784];
  u64* keys = (u64*)smem;
  u32* hist = (u32*)(smem + 4096);
  float4* candbox = (float4*)(smem + 4096);
  float* carea = (float*)(smem + 12288);
  float4* keptbox = (float4*)(smem + 14336);
  float* karea = (float*)(smem + 19136);
  int* kn = (int*)(smem + 20336);
  float* ksc = (float*)(smem + 21536);
  __shared__ u32 wsum[WWAVES], selB[4];
  __shared__ u32 s_cnt;
  __shared__ u64 supW[WWAVES];
  __shared__ u64 mpart[WWAVES][64];
  __shared__ int s_kept;

  const int tid = threadIdx.x;
  const int lane = tid & 63;
  const int w = tid >> 6;
  const u64 lmask = (1ull << lane) - 1ull;
  const int bc = blockIdx.x;
  const int b = bc / NCLS;

  const u32 specRaw = bucketCnt[bc];
  const u32 tailF = tailFlag[bc];

  if (specRaw == 0u && tailF == 0u) {  // no candidates at all
    for (int r = tid; r < MAXDET; r += 512) {
      keptScore[bc * MAXDET + r] = -INFINITY;
      keptN[bc * MAXDET + r] = 0;
    }
    if (tid == 0) keptCount[bc] = 0;
    return;
  }
  if (specRaw > SPECCAP || (tailF != 0u && specRaw < TARGETK)) {
    slow_path(boxes, cls, bc, keptScore, keptN, keptCount, ghist, gtail, smem);
    return;
  }
  const u32 specCount = specRaw;
  const u32 target = (tailF == 0u)
                         ? (specCount < TARGETK ? specCount : TARGETK)
                         : TARGETK;

  const u64* bk = bucketKeys + (size_t)bc * SPECCAP;
  for (int i = tid; i < NHB; i += 512) hist[i] = 0u;
  if (tid == 0) { s_cnt = 0u; s_kept = 0; }
  __syncthreads();
  for (int i = tid; i < (int)specCount; i += 512) {  // global read #1 (L2-hot)
    u32 bits = (u32)(bk[i] >> 32);
    u32 h = (bits >> 9) - HB0;
    if (h > NHB - 1) h = NHB - 1;
    atomicAdd(&hist[h], 1u);
  }
  __syncthreads();

  suffix_fast<NHB, 512>(hist, target, wsum, selB);
  const u32 F0 = selB[0];
  const u32 selCount = selB[1];
  if (selCount > CAP) {
    __syncthreads();
    slow_path(boxes, cls, bc, keptScore, keptN, keptCount, ghist, gtail, smem);
    return;
  }

  const int iters = (int)((specCount + 511u) >> 9);
  for (int it2 = 0; it2 < iters; ++it2) {            // global read #2 (L2-hot)
    u32 idx = (u32)it2 * 512u + (u32)tid;
    bool act = idx < specCount;
    u64 key = act ? bk[idx] : 0ull;
    u32 bits = (u32)(key >> 32);
    u32 h = (bits >> 9) - HB0;
    if (h > NHB - 1) h = NHB - 1;
    bool sel = act && (h >= F0);
    u64 ms = __ballot(sel);
    if (ms) {
      u32 bs;
      if (lane == 0) bs = atomicAdd(&s_cnt, (u32)__popcll(ms));
      bs = __shfl(bs, 0);
      if (sel) keys[bs + (u32)__popcll(ms & lmask)] = key;
    }
  }
  __syncthreads();
  for (int i = (int)selCount + tid; i < CAP; i += 512) keys[i] = 0ull;
  __syncthreads();

  bitonic_sort<512>(keys, CAP, tid);

  // Gather candidate boxes (hist dead; candbox/carea alias it).
  for (int i = tid; i < (int)selCount; i += 512) {
    int pos = CAP - 1 - i;
    u32 n = ~((u32)keys[pos]);
    float4 bb = ((const float4*)boxes)[(size_t)b * NBOX + n];
    candbox[pos] = bb;
    carea[pos] = __fmul_rn(__fsub_rn(bb.z, bb.x), __fsub_rn(bb.w, bb.y));
  }
  __syncthreads();

  // Tile-parallel greedy walk (round-13 structure, frozen).
  const u32 ntile = (selCount + 63u) >> 6;
  for (u32 t = 0; t < ntile; ++t) {
    const int kept0 = s_kept;
    if (kept0 >= MAXDET) break;
    const u32 r = t * 64u + (u32)lane;
    const bool valid = r < selCount;
    const int si = valid ? (CAP - 1 - (int)r) : (CAP - 1);
    float4 mybox = candbox[si];
    float marea = carea[si];
    bool sup = false;
    for (int k = w; k < kept0; k += WWAVES) {
      float4 kb = keptbox[k];
      if (iou_sup_fast(kb.x, kb.y, kb.z, kb.w, karea[k],
                       mybox.x, mybox.y, mybox.z, mybox.w, marea))
        sup = true;
    }
    u64 bal = __ballot(sup);
    if (lane == 0) supW[w] = bal;
    u64 mw = 0ull;
    const int ebase = w * 8;
#pragma unroll
    for (int ee = 0; ee < 8; ++ee) {
      const int e = ebase + ee;
      int ei = CAP - 1 - (int)(t * 64u) - e;
      float4 eb = candbox[ei];
      if (e < lane && iou_sup_fast(eb.x, eb.y, eb.z, eb.w, carea[ei],
                                   mybox.x, mybox.y, mybox.z, mybox.w, marea))
        mw |= 1ull << e;
    }
    mpart[w][lane] = mw;
    __syncthreads();
    if (w == 0) {
      u64 prior = 0ull, m = 0ull;
#pragma unroll
      for (int ww = 0; ww < WWAVES; ++ww) {
        prior |= supW[ww];
        m |= mpart[ww][lane];
      }
      u64 remaining = __ballot(valid) & ~prior;
      u64 keptmask = 0ull;
      const int room = MAXDET - kept0;
      while (remaining != 0ull && (int)__popcll(keptmask) < room) {
        int j = __ffsll((long long)remaining) - 1;
        keptmask |= 1ull << j;
        remaining &= ~(1ull << j);
        u64 supj = __ballot(((m >> j) & 1ull) != 0ull);
        remaining &= ~supj;
      }
      if ((keptmask >> lane) & 1ull) {
        int pos = kept0 + (int)__popcll(keptmask & lmask);
        u64 mykey = keys[CAP - 1 - (int)r];
        keptbox[pos] = mybox;
        karea[pos] = marea;
        kn[pos] = (int)(~((u32)mykey));
        ksc[pos] = __uint_as_float((u32)(mykey >> 32));
      }
      if (lane == 0) s_kept = kept0 + (int)__popcll(keptmask);
    }
    __syncthreads();
  }

  const int kept = s_kept;
  const bool exhausted = (kept < MAXDET) && (selCount < specCount || tailF != 0u);
  if (exhausted) {
    __syncthreads();
    slow_path(boxes, cls, bc, keptScore, keptN, keptCount, ghist, gtail, smem);
    return;
  }
  for (int rr = tid; rr < MAXDET; rr += 512) {
    keptScore[bc * MAXDET + rr] = (rr < kept) ? ksc[rr] : -INFINITY;
    keptN[bc * MAXDET + rr] = (rr < kept) ? kn[rr] : 0;
  }
  if (tid == 0) keptCount[bc] = kept;
  for (int rr = tid; rr < kept; rr += 512) {
    float s = ksc[rr];
    if (s > SPEC_THRF) {
      u32 h = (__float_as_uint(s) >> 9) - HB0;
      if (h > NHB - 1) h = NHB - 1;
      atomicAdd(&ghist[b * NHB + h], 1u);
    } else {
      atomicAdd(&gtail[b], 1u);
    }
  }
}

// Top-k + outputs (unchanged).
__global__ __launch_bounds__(256) void k_osort(const float* __restrict__ boxes,
                                               const float* __restrict__ rel,
                                               const float* __restrict__ keptScore,
                                               const int* __restrict__ keptN,
                                               const u32* __restrict__ ghist,
                                               const u32* __restrict__ gtail,
                                               float* __restrict__ out) {
  __shared__ u64 keys[1024];
  __shared__ u32 wsum[4], selB[4];
  __shared__ u32 s_cnt;
  const int tid = threadIdx.x;
  const int lane = tid & 63;
  const u64 lmask = (1ull << lane) - 1ull;
  const int b = blockIdx.x;
  const float4* ks4 = (const float4*)(keptScore + (size_t)b * NTOT);

  if (tid == 0) s_cnt = 0u;
  suffix_fast<NHB, 256>(ghist + (size_t)b * NHB, (u32)MAXDET, wsum, selB);
  const u32 specTotal = selB[3];
  const u32 totalAll = specTotal + gtail[b];
  const u32 target = totalAll < (u32)MAXDET ? totalAll : (u32)MAXDET;
  const u32 F0 = selB[0];
  const u32 selSpec = selB[1];
  const bool fast = (totalAll != 0u) && (specTotal >= target) && (selSpec <= (u32)CAP);
  int SZ = CAP;

  if (totalAll != 0u) {
    if (fast) {
      for (int base = 0; base < NTOT / 4; base += 2048) {
        float4 v[8];
#pragma unroll
        for (int p = 0; p < 8; ++p) {
          int q = base + tid + (p << 8);
          if (q < NTOT / 4) v[p] = ks4[q];
        }
#pragma unroll
        for (int p = 0; p < 8; ++p) {
          int q = base + tid + (p << 8);
          if (q < NTOT / 4) {
            float vv[4] = {v[p].x, v[p].y, v[p].z, v[p].w};
#pragma unroll
            for (int e = 0; e < 4; ++e) {
              float s = vv[e];
              bool sel = false;
              u32 bits = 0;
              if (s > SPEC_THRF) {
                bits = __float_as_uint(s);
                u32 h = (bits >> 9) - HB0;
                if (h > NHB - 1) h = NHB - 1;
                sel = (h >= F0);
              }
              u64 ms = __ballot(sel);
              if (ms) {
                u32 bs;
                if (lane == 0) bs = atomicAdd(&s_cnt, (u32)__popcll(ms));
                bs = __shfl(bs, 0);
                if (sel)
                  keys[bs + (u32)__popcll(ms & lmask)] =
                      ((u64)bits << 32) | (~(u32)(q * 4 + e));
              }
            }
          }
        }
      }
      __syncthreads();
      for (int i = (int)selSpec + tid; i < CAP; i += 256) keys[i] = 0ull;
      __syncthreads();
      bitonic_sort<256>(keys, CAP, tid);
      SZ = CAP;
    } else {
      if (tid < 64) {
        const int c0 = lane, c1 = 64 + lane;
        const bool has1 = (c1 < NCLS);
        const float* ls0 = keptScore + ((size_t)b * NCLS + c0) * MAXDET;
        const float* ls1 = keptScore + ((size_t)b * NCLS + (has1 ? c1 : c0)) * MAXDET;
        int h0 = 0, h1 = 0;
        float v0 = ls0[0], w0v = ls0[1];
        float v1 = has1 ? ls1[0] : -INFINITY;
        float w1v = has1 ? ls1[1] : -INFINITY;
        for (int r = 0; r < (int)target; ++r) {
          float bs; int bcl;
          if (has1 && v1 > v0) { bs = v1; bcl = c1; } else { bs = v0; bcl = c0; }
#pragma unroll
          for (int off = 32; off > 0; off >>= 1) {
            float os = __shfl_xor(bs, off);
            int oc = __shfl_xor(bcl, off);
            if (os > bs || (os == bs && oc < bcl)) { bs = os; bcl = oc; }
          }
          if (bcl == c0) {
            keys[1023 - r] = ((u64)__float_as_uint(bs) << 32) | (~(u32)(c0 * MAXDET + h0));
            ++h0; v0 = w0v; w0v = (h0 + 1 < MAXDET) ? ls0[h0 + 1] : -INFINITY;
          } else if (has1 && bcl == c1) {
            keys[1023 - r] = ((u64)__float_as_uint(bs) << 32) | (~(u32)(c1 * MAXDET + h1));
            ++h1; v1 = w1v; w1v = (h1 + 1 < MAXDET) ? ls1[h1 + 1] : -INFINITY;
          }
        }
      }
      __syncthreads();
      SZ = 1024;
    }
  }

  for (int r = tid; r < MAXDET; r += 256) {
    const bool valid = (u32)r < target;
    float s = -1.0f, pm = -1.0f, pl = -1.0f, cl = -1.0f;
    float4 ob; ob.x = ob.y = ob.z = ob.w = -1.0f;
    if (valid) {
      u64 key = keys[SZ - 1 - r];
      u32 fp = ~((u32)key);
      int c = (int)(fp / MAXDET);
      int slot = (int)(fp - (u32)c * MAXDET);
      int n = keptN[((size_t)b * NCLS + c) * MAXDET + slot];
      s = __uint_as_float((u32)(key >> 32));
      cl = (float)c;
      size_t nb = (size_t)b * NBOX + (u32)n;
      ob = ((const float4*)boxes)[nb];
      const float* rp = rel + nb * NREL;
      float vr[NREL];
#pragma unroll
      for (int p = 0; p < NREL; ++p) vr[p] = rp[p];
      float best = vr[0]; int bi = 0;
#pragma unroll
      for (int p = 1; p < NREL; ++p) { if (vr[p] > best) { best = vr[p]; bi = p; } }
      pm = best; pl = (float)bi;
    }
    ((float4*)out)[(size_t)b * MAXDET + r] = ob;
    const int sbase = NBATCH * MAXDET * 4;
    out[sbase + b * MAXDET + r] = s;
    out[sbase + NBATCH * MAXDET + b * MAXDET + r] = cl;
    out[sbase + 2 * NBATCH * MAXDET + b * MAXDET + r] = pm;
    out[sbase + 3 * NBATCH * MAXDET + b * MAXDET + r] = pl;
  }
}

extern "C" void kernel_launch(void* const* d_in, const int* in_sizes, int n_in,
                              void* d_out, int out_size, void* d_ws, size_t ws_size,
                              hipStream_t stream) {
  (void)in_sizes; (void)n_in; (void)out_size; (void)ws_size;
  const float* boxes = (const float*)d_in[0];
  const float* cls   = (const float*)d_in[1];
  const float* rel   = (const float*)d_in[2];
  float* out = (float*)d_out;
  char* ws = (char*)d_ws;

  const size_t NP = NBATCH * NCLS;  // 640 problems
  size_t off = 0;
  const size_t oKeptScore = off; off += NP * MAXDET * 4;
  const size_t oKeptN     = off; off += NP * MAXDET * 4;
  const size_t oKeptCount = off; off += NP * 4;
  const size_t oBucketCnt = off; off += NP * 4;
  const size_t oTailFlag  = off; off += NP * 4;
  const size_t oGtail     = off; off += NBATCH * 4;
  off = (off + 7) & ~(size_t)7;
  const size_t oGhist     = off; off += (size_t)NBATCH * NHB * 4;
  off = (off + 7) & ~(size_t)7;
  const size_t oBucketKeys = off; off += NP * SPECCAP * 8;

  float* keptScore = (float*)(ws + oKeptScore);
  int* keptN = (int*)(ws + oKeptN);
  int* keptCount = (int*)(ws + oKeptCount);
  u32* bucketCnt = (u32*)(ws + oBucketCnt);
  u32* tailFlag = (u32*)(ws + oTailFlag);
  u32* gtail = (u32*)(ws + oGtail);
  u32* ghist = (u32*)(ws + oGhist);
  u64* bucketKeys = (u64*)(ws + oBucketKeys);

  const int gBlocks = (QTOT + QPB - 1) / QPB;  // 157 per batch

  k_init<<<NBATCH, 256, 0, stream>>>(ghist, gtail, bucketCnt, tailFlag);
  k_gather<<<dim3(gBlocks, NBATCH), 256, 0, stream>>>(cls, bucketKeys,
                                                      bucketCnt, tailFlag);
  k_nms<<<NP, 512, 0, stream>>>(boxes, cls, bucketKeys, bucketCnt, tailFlag,
                                keptScore, keptN, keptCount, ghist, gtail);
  k_osort<<<NBATCH, 256, 0, stream>>>(boxes, rel, keptScore, keptN, ghist, gtail, out);
}

// Round 19
// 128.299 us; speedup vs baseline: 4.1062x; 1.0001x over previous
//
#include <hip/hip_runtime.h>
#include <hip/hip_bf16.h>
#include <math.h>

#define NBATCH 8
#define NBOX   20000
#define NCLS   80
#define NREL   51
#define MAXDET 300
#define NTOT   (NCLS * MAXDET)      // 24000
#define CAP    512
#define SPECCAP 2560
#define NHB    3584                 // 512-ULP buckets over (0.9, 1.0]
#define HB0    (0x3F666666u >> 9)   // bucket base = bits(0.9f) >> 9
#define TARGETK 360u                // validated on this data in round 12 (6 walk tiles)
#define SCORE_THR 0.05f
#define SPEC_THRF 0.9f
#define WWAVES 8
#define QPB    2560                 // float4 per gather block (= 128 boxes)
#define QTOT   (NBOX * NCLS / 4)    // 400000 float4 per batch
#define KCAP   40                   // staged keys per class per block (~8 sigma)

typedef unsigned long long u64;
typedef unsigned int u32;

// IoU > 0.5, explicit IEEE div (slow path only).
__device__ __forceinline__ bool iou_sup(float ax1, float ay1, float ax2, float ay2, float aarea,
                                        float bx1, float by1, float bx2, float by2, float barea) {
  float ix1 = fmaxf(ax1, bx1);
  float iy1 = fmaxf(ay1, by1);
  float ix2 = fminf(ax2, bx2);
  float iy2 = fminf(ay2, by2);
  float dw = fmaxf(__fsub_rn(ix2, ix1), 0.0f);
  float dh = fmaxf(__fsub_rn(iy2, iy1), 0.0f);
  float inter = __fmul_rn(dw, dh);
  float uni = __fsub_rn(__fadd_rn(aarea, barea), inter);
  if (!(uni > 0.0f)) return false;
  return __fdiv_rn(inter, uni) > 0.5f;
}

__device__ __forceinline__ bool iou_gt_half(float ax1, float ay1, float ax2, float ay2,
                                            float bx1, float by1, float bx2, float by2) {
  float aa = __fmul_rn(__fsub_rn(ax2, ax1), __fsub_rn(ay2, ay1));
  float ab = __fmul_rn(__fsub_rn(bx2, bx1), __fsub_rn(by2, by1));
  return iou_sup(ax1, ay1, ax2, ay2, aa, bx1, by1, bx2, by2, ab);
}

// Bit-exact div-free IoU>0.5 in PURE f32 (proof in round-9 notes).
__device__ __forceinline__ bool iou_sup_fast(float ax1, float ay1, float ax2, float ay2,
                                             float aarea, float bx1, float by1, float bx2,
                                             float by2, float barea) {
  float ix1 = fmaxf(ax1, bx1);
  float iy1 = fmaxf(ay1, by1);
  float ix2 = fminf(ax2, bx2);
  float iy2 = fminf(ay2, by2);
  float dw = fmaxf(__fsub_rn(ix2, ix1), 0.0f);
  float dh = fmaxf(__fsub_rn(iy2, iy1), 0.0f);
  float inter = __fmul_rn(dw, dh);
  float uni = __fsub_rn(__fadd_rn(aarea, barea), inter);
  return (uni > 0.0f) && (inter > __fmul_rn(0.5f, uni));
}

#define CEXR(x, y, asc) { bool sw_ = (asc) ? ((x) > (y)) : ((x) < (y)); \
                          if (sw_) { u64 t_ = (x); (x) = (y); (y) = t_; } }

// Bitonic sort ascending over SZ u64 keys in LDS.
template <int THREADS>
__device__ __forceinline__ void bitonic_sort(u64* keys, int SZ, int tid) {
  for (int k = 2; k <= SZ; k <<= 1) {
    for (int j = k >> 1; j >= 4; j >>= 1) {
      for (int v = tid; v < (SZ >> 1); v += THREADS) {
        int i = ((v & ~(j - 1)) << 1) | (v & (j - 1));
        int p = i | j;
        bool asc = ((i & k) == 0);
        u64 a = keys[i], b = keys[p];
        bool sw = asc ? (a > b) : (a < b);
        if (sw) { keys[i] = b; keys[p] = a; }
      }
      __syncthreads();
    }
    if (tid < (SZ >> 2)) {
      ulonglong2* k2 = (ulonglong2*)keys;
      ulonglong2 lo = k2[tid * 2], hi = k2[tid * 2 + 1];
      u64 a = lo.x, b = lo.y, c = hi.x, d = hi.y;
      int i0 = tid << 2;
      if (k == 2) {
        CEXR(a, b, true); CEXR(c, d, false);
      } else {
        bool asc = ((i0 & k) == 0);
        CEXR(a, c, asc); CEXR(b, d, asc);  // j = 2
        CEXR(a, b, asc); CEXR(c, d, asc);  // j = 1
      }
      lo.x = a; lo.y = b; hi.x = c; hi.y = d;
      k2[tid * 2] = lo; k2[tid * 2 + 1] = hi;
    }
    __syncthreads();
  }
}

// Barrier-light suffix select over NB buckets: minimal suffix >= min(total, cap).
// sout: [0]=bucket [1]=sel [2]=above [3]=total.
template <int NB, int THREADS>
__device__ __forceinline__ void suffix_fast(const u32* hist, u32 cap, u32* wsum, u32* sout) {
  const int tid = threadIdx.x, lane = tid & 63, w = tid >> 6;
  const int NW = THREADS / 64;
  const int G = NB / THREADS;
  u32 v = 0;
  const int hb = tid * G;
#pragma unroll
  for (int t = 0; t < G; ++t) v += hist[hb + t];
  u32 s = v;
#pragma unroll
  for (int off = 1; off < 64; off <<= 1) {
    u32 t2 = __shfl_down(s, off);
    if (lane + off < 64) s += t2;
  }
  if (lane == 0) wsum[w] = s;
  __syncthreads();
  u32 total = 0;
#pragma unroll
  for (int ww = 0; ww < NW; ++ww) total += wsum[ww];
  u32 after = 0;
#pragma unroll
  for (int ww = 1; ww < NW; ++ww) if (ww > w) after += wsum[ww];
  u32 inc = s + after;
  u32 exc = inc - v;
  if (tid == 0) {
    sout[3] = total;
    if (total == 0u) { sout[0] = 0u; sout[1] = 0u; sout[2] = 0u; }
  }
  u32 target = total < cap ? total : cap;
  if (total != 0u && inc >= target && exc < target) {  // exactly one thread
    u32 acc = exc;
    for (int u = hb + G - 1; u >= hb; --u) {
      acc += hist[u];
      if (acc >= target) { sout[0] = (u32)u; sout[1] = acc; sout[2] = acc - hist[u]; break; }
    }
  }
  __syncthreads();
}

// Zero all per-launch scratch.
__global__ __launch_bounds__(256) void k_init(u32* __restrict__ ghist,
                                              u32* __restrict__ gtail,
                                              u32* __restrict__ bucketCnt,
                                              u32* __restrict__ tailFlag) {
  const int b = blockIdx.x;
  const int tid = threadIdx.x;
  for (int i = tid; i < NHB; i += 256) ghist[b * NHB + i] = 0u;
  if (tid == 0) gtail[b] = 0u;
  for (int i = tid; i < NCLS; i += 256) {
    bucketCnt[b * NCLS + i] = 0u;
    tailFlag[b * NCLS + i] = 0u;
  }
}

// Pure streaming gather (round-17, frozen).
__global__ __launch_bounds__(256) void k_gather(const float* __restrict__ cls,
                                                u64* __restrict__ bucketKeys,
                                                u32* __restrict__ bucketCnt,
                                                u32* __restrict__ tailFlag) {
  __shared__ u64 stKeys[NCLS][KCAP];         // 25600 B
  __shared__ u32 stCnt[NCLS], sBase[NCLS], stOvf[NCLS], tailL[NCLS];
  const int tid = threadIdx.x;
  const int lane = tid & 63;
  const int w = tid >> 6;
  const int b = blockIdx.y;
  const int q0 = blockIdx.x * QPB;
  const int qend = (q0 + QPB < QTOT) ? (q0 + QPB) : QTOT;
  const float4* src = (const float4*)(cls + (size_t)b * NBOX * NCLS);

  for (int i = tid; i < NCLS; i += 256) { stCnt[i] = 0u; stOvf[i] = 0u; tailL[i] = 0u; }
  __syncthreads();

  for (int base = q0; base < qend; base += 2048) {
    float4 v[8];
#pragma unroll
    for (int p = 0; p < 8; ++p) {
      int q = base + tid + (p << 8);
      if (q < qend) v[p] = src[q];
    }
#pragma unroll
    for (int p = 0; p < 8; ++p) {
      int q = base + tid + (p << 8);
      if (q < qend) {
        int nn = q / (NCLS / 4);
        int cb = (q - nn * (NCLS / 4)) * 4;
        float vv[4] = {v[p].x, v[p].y, v[p].z, v[p].w};
#pragma unroll
        for (int e = 0; e < 4; ++e) {
          float s = vv[e];
          int c = cb + e;
          if (s > SPEC_THRF) {
            u32 pos = atomicAdd(&stCnt[c], 1u);
            if (pos < KCAP)
              stKeys[c][pos] = ((u64)__float_as_uint(s) << 32) | (~(u32)nn);
            else
              stOvf[c] = 1u;            // benign same-value race
          } else if (s > SCORE_THR) {
            if (tailL[c] == 0u) tailL[c] = 1u;  // broadcast read, rare write
          }
        }
      }
    }
  }
  __syncthreads();

  if (tid < NCLS) {
    if (tailL[tid]) tailFlag[b * NCLS + tid] = 1u;   // benign same-value race
    u32 cnt = stCnt[tid];
    u32 wr = cnt < KCAP ? cnt : (u32)KCAP;
    u32 add = wr + (stOvf[tid] ? (u32)(SPECCAP + 1) : 0u);
    u32 base = 0;
    if (add) base = atomicAdd(&bucketCnt[b * NCLS + tid], add);
    sBase[tid] = base;
    stCnt[tid] = wr;
  }
  __syncthreads();

  for (int c = w; c < NCLS; c += 4) {
    u32 cnt = stCnt[c];
    u32 base = sBase[c];
    u64* dst = bucketKeys + (size_t)(b * NCLS + c) * SPECCAP;
    for (u32 i = lane; i < cnt; i += 64) {
      u32 pos = base + i;
      if (pos < SPECCAP) dst[pos] = stKeys[c][i];
    }
  }
}

// Exact reference-style greedy NMS (slow path), 512-thread, inline from k_nms.
__device__ void slow_path(const float* __restrict__ boxes,
                          const float* __restrict__ cls, int bc,
                          float* __restrict__ keptScore, int* __restrict__ keptN,
                          int* __restrict__ keptCount,
                          u32* __restrict__ ghist, u32* __restrict__ gtail,
                          char* smem) {
  u32* sup = (u32*)smem;                       // [(NBOX+31)/32] u32 @0
  u64* red = (u64*)(smem + 2560);              // [512] u64 @2560
  float4* sbx = (float4*)(smem + 6656);
  int* s_kept = (int*)(smem + 6672);
  const int tid = threadIdx.x;
  const int b = bc / NCLS, c = bc % NCLS;
  const float* col = cls + (size_t)b * NBOX * NCLS + c;

  for (int i = tid; i < (NBOX + 31) / 32; i += 512) sup[i] = 0u;
  if (tid == 0) *s_kept = 0;
  __syncthreads();
  for (int it = 0; it < MAXDET; ++it) {
    u64 best = 0ull;
    for (int n = tid; n < NBOX; n += 512) {
      if ((sup[n >> 5] >> (n & 31)) & 1u) continue;
      float s = col[(size_t)n * NCLS];
      if (s > SCORE_THR) {
        u64 key = ((u64)__float_as_uint(s) << 32) | (~(u32)n);
        if (key > best) best = key;
      }
    }
    red[tid] = best;
    __syncthreads();
    for (int off = 256; off > 0; off >>= 1) {
      if (tid < off) { u64 o = red[tid + off]; if (o > red[tid]) red[tid] = o; }
      __syncthreads();
    }
    u64 win = red[0];
    if (win == 0ull) break;
    u32 nw = ~((u32)win);
    if (tid == 0) {
      int k = *s_kept;
      keptScore[bc * MAXDET + k] = __uint_as_float((u32)(win >> 32));
      keptN[bc * MAXDET + k] = (int)nw;
      *s_kept = k + 1;
      *sbx = ((const float4*)boxes)[(size_t)b * NBOX + nw];
    }
    __syncthreads();
    float4 bx = *sbx;
    for (int n = tid; n < NBOX; n += 512) {
      float4 cb = ((const float4*)boxes)[(size_t)b * NBOX + n];
      if (iou_gt_half(bx.x, bx.y, bx.z, bx.w, cb.x, cb.y, cb.z, cb.w))
        atomicOr(&sup[n >> 5], 1u << (n & 31));
    }
    if (tid == 0) atomicOr(&sup[nw >> 5], 1u << (nw & 31));
    __syncthreads();
  }
  __syncthreads();
  const int kept = *s_kept;
  for (int r = kept + tid; r < MAXDET; r += 512) {
    keptScore[bc * MAXDET + r] = -INFINITY;
    keptN[bc * MAXDET + r] = 0;
  }
  for (int rr = tid; rr < kept; rr += 512) {
    float s = keptScore[bc * MAXDET + rr];
    if (s > SPEC_THRF) {
      u32 h = (__float_as_uint(s) >> 9) - HB0;
      if (h > NHB - 1) h = NHB - 1;
      atomicAdd(&ghist[b * NHB + h], 1u);
    } else {
      atomicAdd(&gtail[b], 1u);
    }
  }
  if (tid == 0) keptCount[bc] = kept;
}

// Fused per-(b,c) kernel (round-18 LDS-slim, frozen): hist + compact read the
// L2-resident bucket directly -> bitonic-512 -> round-13 walk (now 6 tiles).
__global__ __launch_bounds__(512) void k_nms(const float* __restrict__ boxes,
                                             const float* __restrict__ cls,
                                             const u64* __restrict__ bucketKeys,
                                             const u32* __restrict__ bucketCnt,
                                             const u32* __restrict__ tailFlag,
                                             float* __restrict__ keptScore,
                                             int* __restrict__ keptN,
                                             int* __restrict__ keptCount,
                                             u32* __restrict__ ghist,
                                             u32* __restrict__ gtail) {
  __shared__ __align__(16) char smem[22784];
  u64* keys = (u64*)smem;
  u32* hist = (u32*)(smem + 4096);
  float4* candbox = (float4*)(smem + 4096);
  float* carea = (float*)(smem + 12288);
  float4* keptbox = (float4*)(smem + 14336);
  float* karea = (float*)(smem + 19136);
  int* kn = (int*)(smem + 20336);
  float* ksc = (float*)(smem + 21536);
  __shared__ u32 wsum[WWAVES], selB[4];
  __shared__ u32 s_cnt;
  __shared__ u64 supW[WWAVES];
  __shared__ u64 mpart[WWAVES][64];
  __shared__ int s_kept;

  const int tid = threadIdx.x;
  const int lane = tid & 63;
  const int w = tid >> 6;
  const u64 lmask = (1ull << lane) - 1ull;
  const int bc = blockIdx.x;
  const int b = bc / NCLS;

  const u32 specRaw = bucketCnt[bc];
  const u32 tailF = tailFlag[bc];

  if (specRaw == 0u && tailF == 0u) {
    for (int r = tid; r < MAXDET; r += 512) {
      keptScore[bc * MAXDET + r] = -INFINITY;
      keptN[bc * MAXDET + r] = 0;
    }
    if (tid == 0) keptCount[bc] = 0;
    return;
  }
  if (specRaw > SPECCAP || (tailF != 0u && specRaw < TARGETK)) {
    slow_path(boxes, cls, bc, keptScore, keptN, keptCount, ghist, gtail, smem);
    return;
  }
  const u32 specCount = specRaw;
  const u32 target = (tailF == 0u)
                         ? (specCount < TARGETK ? specCount : TARGETK)
                         : TARGETK;

  const u64* bk = bucketKeys + (size_t)bc * SPECCAP;
  for (int i = tid; i < NHB; i += 512) hist[i] = 0u;
  if (tid == 0) { s_cnt = 0u; s_kept = 0; }
  __syncthreads();
  for (int i = tid; i < (int)specCount; i += 512) {
    u32 bits = (u32)(bk[i] >> 32);
    u32 h = (bits >> 9) - HB0;
    if (h > NHB - 1) h = NHB - 1;
    atomicAdd(&hist[h], 1u);
  }
  __syncthreads();

  suffix_fast<NHB, 512>(hist, target, wsum, selB);
  const u32 F0 = selB[0];
  const u32 selCount = selB[1];
  if (selCount > CAP) {
    __syncthreads();
    slow_path(boxes, cls, bc, keptScore, keptN, keptCount, ghist, gtail, smem);
    return;
  }

  const int iters = (int)((specCount + 511u) >> 9);
  for (int it2 = 0; it2 < iters; ++it2) {
    u32 idx = (u32)it2 * 512u + (u32)tid;
    bool act = idx < specCount;
    u64 key = act ? bk[idx] : 0ull;
    u32 bits = (u32)(key >> 32);
    u32 h = (bits >> 9) - HB0;
    if (h > NHB - 1) h = NHB - 1;
    bool sel = act && (h >= F0);
    u64 ms = __ballot(sel);
    if (ms) {
      u32 bs;
      if (lane == 0) bs = atomicAdd(&s_cnt, (u32)__popcll(ms));
      bs = __shfl(bs, 0);
      if (sel) keys[bs + (u32)__popcll(ms & lmask)] = key;
    }
  }
  __syncthreads();
  for (int i = (int)selCount + tid; i < CAP; i += 512) keys[i] = 0ull;
  __syncthreads();

  bitonic_sort<512>(keys, CAP, tid);

  for (int i = tid; i < (int)selCount; i += 512) {
    int pos = CAP - 1 - i;
    u32 n = ~((u32)keys[pos]);
    float4 bb = ((const float4*)boxes)[(size_t)b * NBOX + n];
    candbox[pos] = bb;
    carea[pos] = __fmul_rn(__fsub_rn(bb.z, bb.x), __fsub_rn(bb.w, bb.y));
  }
  __syncthreads();

  const u32 ntile = (selCount + 63u) >> 6;
  for (u32 t = 0; t < ntile; ++t) {
    const int kept0 = s_kept;
    if (kept0 >= MAXDET) break;
    const u32 r = t * 64u + (u32)lane;
    const bool valid = r < selCount;
    const int si = valid ? (CAP - 1 - (int)r) : (CAP - 1);
    float4 mybox = candbox[si];
    float marea = carea[si];
    bool sup = false;
    for (int k = w; k < kept0; k += WWAVES) {
      float4 kb = keptbox[k];
      if (iou_sup_fast(kb.x, kb.y, kb.z, kb.w, karea[k],
                       mybox.x, mybox.y, mybox.z, mybox.w, marea))
        sup = true;
    }
    u64 bal = __ballot(sup);
    if (lane == 0) supW[w] = bal;
    u64 mw = 0ull;
    const int ebase = w * 8;
#pragma unroll
    for (int ee = 0; ee < 8; ++ee) {
      const int e = ebase + ee;
      int ei = CAP - 1 - (int)(t * 64u) - e;
      float4 eb = candbox[ei];
      if (e < lane && iou_sup_fast(eb.x, eb.y, eb.z, eb.w, carea[ei],
                                   mybox.x, mybox.y, mybox.z, mybox.w, marea))
        mw |= 1ull << e;
    }
    mpart[w][lane] = mw;
    __syncthreads();
    if (w == 0) {
      u64 prior = 0ull, m = 0ull;
#pragma unroll
      for (int ww = 0; ww < WWAVES; ++ww) {
        prior |= supW[ww];
        m |= mpart[ww][lane];
      }
      u64 remaining = __ballot(valid) & ~prior;
      u64 keptmask = 0ull;
      const int room = MAXDET - kept0;
      while (remaining != 0ull && (int)__popcll(keptmask) < room) {
        int j = __ffsll((long long)remaining) - 1;
        keptmask |= 1ull << j;
        remaining &= ~(1ull << j);
        u64 supj = __ballot(((m >> j) & 1ull) != 0ull);
        remaining &= ~supj;
      }
      if ((keptmask >> lane) & 1ull) {
        int pos = kept0 + (int)__popcll(keptmask & lmask);
        u64 mykey = keys[CAP - 1 - (int)r];
        keptbox[pos] = mybox;
        karea[pos] = marea;
        kn[pos] = (int)(~((u32)mykey));
        ksc[pos] = __uint_as_float((u32)(mykey >> 32));
      }
      if (lane == 0) s_kept = kept0 + (int)__popcll(keptmask);
    }
    __syncthreads();
  }

  const int kept = s_kept;
  const bool exhausted = (kept < MAXDET) && (selCount < specCount || tailF != 0u);
  if (exhausted) {
    __syncthreads();
    slow_path(boxes, cls, bc, keptScore, keptN, keptCount, ghist, gtail, smem);
    return;
  }
  for (int rr = tid; rr < MAXDET; rr += 512) {
    keptScore[bc * MAXDET + rr] = (rr < kept) ? ksc[rr] : -INFINITY;
    keptN[bc * MAXDET + rr] = (rr < kept) ? kn[rr] : 0;
  }
  if (tid == 0) keptCount[bc] = kept;
  for (int rr = tid; rr < kept; rr += 512) {
    float s = ksc[rr];
    if (s > SPEC_THRF) {
      u32 h = (__float_as_uint(s) >> 9) - HB0;
      if (h > NHB - 1) h = NHB - 1;
      atomicAdd(&ghist[b * NHB + h], 1u);
    } else {
      atomicAdd(&gtail[b], 1u);
    }
  }
}

// Top-k + outputs (unchanged).
__global__ __launch_bounds__(256) void k_osort(const float* __restrict__ boxes,
                                               const float* __restrict__ rel,
                                               const float* __restrict__ keptScore,
                                               const int* __restrict__ keptN,
                                               const u32* __restrict__ ghist,
                                               const u32* __restrict__ gtail,
                                               float* __restrict__ out) {
  __shared__ u64 keys[1024];
  __shared__ u32 wsum[4], selB[4];
  __shared__ u32 s_cnt;
  const int tid = threadIdx.x;
  const int lane = tid & 63;
  const u64 lmask = (1ull << lane) - 1ull;
  const int b = blockIdx.x;
  const float4* ks4 = (const float4*)(keptScore + (size_t)b * NTOT);

  if (tid == 0) s_cnt = 0u;
  suffix_fast<NHB, 256>(ghist + (size_t)b * NHB, (u32)MAXDET, wsum, selB);
  const u32 specTotal = selB[3];
  const u32 totalAll = specTotal + gtail[b];
  const u32 target = totalAll < (u32)MAXDET ? totalAll : (u32)MAXDET;
  const u32 F0 = selB[0];
  const u32 selSpec = selB[1];
  const bool fast = (totalAll != 0u) && (specTotal >= target) && (selSpec <= (u32)CAP);
  int SZ = CAP;

  if (totalAll != 0u) {
    if (fast) {
      for (int base = 0; base < NTOT / 4; base += 2048) {
        float4 v[8];
#pragma unroll
        for (int p = 0; p < 8; ++p) {
          int q = base + tid + (p << 8);
          if (q < NTOT / 4) v[p] = ks4[q];
        }
#pragma unroll
        for (int p = 0; p < 8; ++p) {
          int q = base + tid + (p << 8);
          if (q < NTOT / 4) {
            float vv[4] = {v[p].x, v[p].y, v[p].z, v[p].w};
#pragma unroll
            for (int e = 0; e < 4; ++e) {
              float s = vv[e];
              bool sel = false;
              u32 bits = 0;
              if (s > SPEC_THRF) {
                bits = __float_as_uint(s);
                u32 h = (bits >> 9) - HB0;
                if (h > NHB - 1) h = NHB - 1;
                sel = (h >= F0);
              }
              u64 ms = __ballot(sel);
              if (ms) {
                u32 bs;
                if (lane == 0) bs = atomicAdd(&s_cnt, (u32)__popcll(ms));
                bs = __shfl(bs, 0);
                if (sel)
                  keys[bs + (u32)__popcll(ms & lmask)] =
                      ((u64)bits << 32) | (~(u32)(q * 4 + e));
              }
            }
          }
        }
      }
      __syncthreads();
      for (int i = (int)selSpec + tid; i < CAP; i += 256) keys[i] = 0ull;
      __syncthreads();
      bitonic_sort<256>(keys, CAP, tid);
      SZ = CAP;
    } else {
      if (tid < 64) {
        const int c0 = lane, c1 = 64 + lane;
        const bool has1 = (c1 < NCLS);
        const float* ls0 = keptScore + ((size_t)b * NCLS + c0) * MAXDET;
        const float* ls1 = keptScore + ((size_t)b * NCLS + (has1 ? c1 : c0)) * MAXDET;
        int h0 = 0, h1 = 0;
        float v0 = ls0[0], w0v = ls0[1];
        float v1 = has1 ? ls1[0] : -INFINITY;
        float w1v = has1 ? ls1[1] : -INFINITY;
        for (int r = 0; r < (int)target; ++r) {
          float bs; int bcl;
          if (has1 && v1 > v0) { bs = v1; bcl = c1; } else { bs = v0; bcl = c0; }
#pragma unroll
          for (int off = 32; off > 0; off >>= 1) {
            float os = __shfl_xor(bs, off);
            int oc = __shfl_xor(bcl, off);
            if (os > bs || (os == bs && oc < bcl)) { bs = os; bcl = oc; }
          }
          if (bcl == c0) {
            keys[1023 - r] = ((u64)__float_as_uint(bs) << 32) | (~(u32)(c0 * MAXDET + h0));
            ++h0; v0 = w0v; w0v = (h0 + 1 < MAXDET) ? ls0[h0 + 1] : -INFINITY;
          } else if (has1 && bcl == c1) {
            keys[1023 - r] = ((u64)__float_as_uint(bs) << 32) | (~(u32)(c1 * MAXDET + h1));
            ++h1; v1 = w1v; w1v = (h1 + 1 < MAXDET) ? ls1[h1 + 1] : -INFINITY;
          }
        }
      }
      __syncthreads();
      SZ = 1024;
    }
  }

  for (int r = tid; r < MAXDET; r += 256) {
    const bool valid = (u32)r < target;
    float s = -1.0f, pm = -1.0f, pl = -1.0f, cl = -1.0f;
    float4 ob; ob.x = ob.y = ob.z = ob.w = -1.0f;
    if (valid) {
      u64 key = keys[SZ - 1 - r];
      u32 fp = ~((u32)key);
      int c = (int)(fp / MAXDET);
      int slot = (int)(fp - (u32)c * MAXDET);
      int n = keptN[((size_t)b * NCLS + c) * MAXDET + slot];
      s = __uint_as_float((u32)(key >> 32));
      cl = (float)c;
      size_t nb = (size_t)b * NBOX + (u32)n;
      ob = ((const float4*)boxes)[nb];
      const float* rp = rel + nb * NREL;
      float vr[NREL];
#pragma unroll
      for (int p = 0; p < NREL; ++p) vr[p] = rp[p];
      float best = vr[0]; int bi = 0;
#pragma unroll
      for (int p = 1; p < NREL; ++p) { if (vr[p] > best) { best = vr[p]; bi = p; } }
      pm = best; pl = (float)bi;
    }
    ((float4*)out)[(size_t)b * MAXDET + r] = ob;
    const int sbase = NBATCH * MAXDET * 4;
    out[sbase + b * MAXDET + r] = s;
    out[sbase + NBATCH * MAXDET + b * MAXDET + r] = cl;
    out[sbase + 2 * NBATCH * MAXDET + b * MAXDET + r] = pm;
    out[sbase + 3 * NBATCH * MAXDET + b * MAXDET + r] = pl;
  }
}

extern "C" void kernel_launch(void* const* d_in, const int* in_sizes, int n_in,
                              void* d_out, int out_size, void* d_ws, size_t ws_size,
                              hipStream_t stream) {
  (void)in_sizes; (void)n_in; (void)out_size; (void)ws_size;
  const float* boxes = (const float*)d_in[0];
  const float* cls   = (const float*)d_in[1];
  const float* rel   = (const float*)d_in[2];
  float* out = (float*)d_out;
  char* ws = (char*)d_ws;

  const size_t NP = NBATCH * NCLS;  // 640 problems
  size_t off = 0;
  const size_t oKeptScore = off; off += NP * MAXDET * 4;
  const size_t oKeptN     = off; off += NP * MAXDET * 4;
  const size_t oKeptCount = off; off += NP * 4;
  const size_t oBucketCnt = off; off += NP * 4;
  const size_t oTailFlag  = off; off += NP * 4;
  const size_t oGtail     = off; off += NBATCH * 4;
  off = (off + 7) & ~(size_t)7;
  const size_t oGhist     = off; off += (size_t)NBATCH * NHB * 4;
  off = (off + 7) & ~(size_t)7;
  const size_t oBucketKeys = off; off += NP * SPECCAP * 8;

  float* keptScore = (float*)(ws + oKeptScore);
  int* keptN = (int*)(ws + oKeptN);
  int* keptCount = (int*)(ws + oKeptCount);
  u32* bucketCnt = (u32*)(ws + oBucketCnt);
  u32* tailFlag = (u32*)(ws + oTailFlag);
  u32* gtail = (u32*)(ws + oGtail);
  u32* ghist = (u32*)(ws + oGhist);
  u64* bucketKeys = (u64*)(ws + oBucketKeys);

  const int gBlocks = (QTOT + QPB - 1) / QPB;  // 157 per batch

  k_init<<<NBATCH, 256, 0, stream>>>(ghist, gtail, bucketCnt, tailFlag);
  k_gather<<<dim3(gBlocks, NBATCH), 256, 0, stream>>>(cls, bucketKeys,
                                                      bucketCnt, tailFlag);
  k_nms<<<NP, 512, 0, stream>>>(boxes, cls, bucketKeys, bucketCnt, tailFlag,
                                keptScore, keptN, keptCount, ghist, gtail);
  k_osort<<<NBATCH, 256, 0, stream>>>(boxes, rel, keptScore, keptN, ghist, gtail, out);
}